// Round 5
// baseline (753.655 us; speedup 1.0000x reference)
//
#include <hip/hip_runtime.h>
#include <hip/hip_bf16.h>
#include <stdint.h>

typedef __bf16 bf16;
typedef signed char i8;
typedef __bf16 v8bf __attribute__((ext_vector_type(8)));
typedef __bf16 v4bf __attribute__((ext_vector_type(4)));
typedef signed char v8i8 __attribute__((ext_vector_type(8)));
typedef int    v4i  __attribute__((ext_vector_type(4)));
typedef float  f32x16 __attribute__((ext_vector_type(16)));

#define MFMA32(a,b,c)   __builtin_amdgcn_mfma_f32_32x32x16_bf16((a),(b),(c),0,0,0)
#define MFMA_I8(a,b,c)  __builtin_amdgcn_mfma_i32_16x16x64_i8((a),(b),(c),0,0,0)

__device__ __forceinline__ void glds16(const void* g, void* l) {
  __builtin_amdgcn_global_load_lds(
      (const __attribute__((address_space(1))) void*)g,
      (__attribute__((address_space(3))) void*)l, 16, 0, 0);
}

__device__ __forceinline__ float wred_sum(float v) {
#pragma unroll
  for (int o = 32; o; o >>= 1) v += __shfl_xor(v, o);
  return v;
}
__device__ __forceinline__ float wred_max(float v) {
#pragma unroll
  for (int o = 32; o; o >>= 1) v = fmaxf(v, __shfl_xor(v, o));
  return v;
}

__device__ __forceinline__ unsigned int packbf(float a, float b) {
  union { bf16 h[2]; unsigned int u; } x;
  x.h[0] = (bf16)a; x.h[1] = (bf16)b;
  return x.u;
}

// ---------------- dtype sniffer (inputs turned out fp32; keep robust) ----------------
__global__ void k_sniff(const unsigned short* __restrict__ x, int* __restrict__ flag) {
  int cnt = 0;
  for (int i = threadIdx.x; i < 2048; i += 64) {
    const unsigned short u = x[i];
    const int e = (u >> 7) & 0xFF;
    if (u == 0 || (e >= 100 && e <= 140)) cnt++;
  }
#pragma unroll
  for (int o = 32; o; o >>= 1) cnt += __shfl_xor(cnt, o);
  if (threadIdx.x == 0) flag[0] = (cnt >= 1844) ? 0 : 1;  // 0 = bf16, 1 = f32
}

// ---------------- small utility kernels ----------------

__global__ void k_zero(float* p, int n) {
  int i = threadIdx.x;
  if (i < n) p[i] = 0.0f;
}

// zero a float4-aligned buffer; grid = bytes/16/256
__global__ __launch_bounds__(256) void k_zerof(float4* __restrict__ p) {
  p[(size_t)blockIdx.x * 256 + threadIdx.x] = make_float4(0.f, 0.f, 0.f, 0.f);
}

__global__ __launch_bounds__(256) void k_abssum(const void* __restrict__ w, int n,
                                                const int* __restrict__ flag,
                                                float* __restrict__ out) {
  const int tid = threadIdx.x;
  const int f32 = flag[0];
  __shared__ float sred[4];
  float s = 0.0f;
  if (f32) {
    const float4* p = (const float4*)w;
    for (int i = (blockIdx.x * 256 + tid) * 2; i * 4 < n; i += gridDim.x * 512) {
      float4 a = p[i], b = p[i + 1];
      s += fabsf(a.x) + fabsf(a.y) + fabsf(a.z) + fabsf(a.w) +
           fabsf(b.x) + fabsf(b.y) + fabsf(b.z) + fabsf(b.w);
    }
  } else {
    const bf16* p = (const bf16*)w;
    for (int i = (blockIdx.x * 256 + tid) * 8; i < n; i += gridDim.x * 2048) {
      v8bf v = *(const v8bf*)(p + i);
#pragma unroll
      for (int j = 0; j < 8; j++) s += fabsf((float)v[j]);
    }
  }
  s = wred_sum(s);
  if ((tid & 63) == 0) sred[tid >> 6] = s;
  __syncthreads();
  if (tid == 0) atomicAdd(out, sred[0] + sred[1] + sred[2] + sred[3]);
}

// ternary weight quant -> int8
__global__ __launch_bounds__(256) void k_wquant(const void* __restrict__ w, i8* __restrict__ o,
                                                const float* __restrict__ sum, float invn,
                                                const int* __restrict__ flag) {
  const int gid = blockIdx.x * 256 + threadIdx.x;
  const int i = gid * 8;
  const float ws = 1.0f / fmaxf(sum[0] * invn, 1e-5f);
  const int f32 = flag[0];
  float v[8];
  if (f32) {
    float4 a = ((const float4*)w)[gid * 2];
    float4 b = ((const float4*)w)[gid * 2 + 1];
    v[0] = a.x; v[1] = a.y; v[2] = a.z; v[3] = a.w;
    v[4] = b.x; v[5] = b.y; v[6] = b.z; v[7] = b.w;
  } else {
    v8bf t = *(const v8bf*)((const bf16*)w + i);
#pragma unroll
    for (int j = 0; j < 8; j++) v[j] = (float)t[j];
  }
  v8i8 r;
#pragma unroll
  for (int j = 0; j < 8; j++) {
    float t = rintf(v[j] * ws);
    r[j] = (i8)fminf(fmaxf(t, -1.0f), 1.0f);
  }
  *(v8i8*)(o + i) = r;
}

// LayerNorm + per-row absmax quantize -> int8.
template <bool XINT>
__global__ __launch_bounds__(256) void k_lnq(const void* __restrict__ x, const void* __restrict__ g,
                                             const void* __restrict__ b, i8* __restrict__ q,
                                             float* __restrict__ sc, const int* __restrict__ flag) {
  const int row = blockIdx.x, tid = threadIdx.x;
  const int f32 = flag[0];
  __shared__ float sred[4];
  float v[8];
#pragma unroll
  for (int i = 0; i < 8; i++) {
    const size_t idx = (size_t)row * 2048 + tid + 256 * i;
    if (XINT)      v[i] = ((const float*)x)[idx];
    else if (f32)  v[i] = ((const float*)x)[idx];
    else           v[i] = (float)((const bf16*)x)[idx];
  }
  float s = 0.0f;
#pragma unroll
  for (int i = 0; i < 8; i++) s += v[i];
  s = wred_sum(s);
  if ((tid & 63) == 0) sred[tid >> 6] = s;
  __syncthreads();
  const float mean = (sred[0] + sred[1] + sred[2] + sred[3]) * (1.0f / 2048.0f);
  __syncthreads();
  float vs = 0.0f;
#pragma unroll
  for (int i = 0; i < 8; i++) { float d = v[i] - mean; vs += d * d; }
  vs = wred_sum(vs);
  if ((tid & 63) == 0) sred[tid >> 6] = vs;
  __syncthreads();
  const float rstd = rsqrtf((sred[0] + sred[1] + sred[2] + sred[3]) * (1.0f / 2048.0f) + 1e-6f);
  __syncthreads();
  float hq[8];
  float am = 0.0f;
#pragma unroll
  for (int i = 0; i < 8; i++) {
    const int c = tid + 256 * i;
    const float gv = f32 ? ((const float*)g)[c] : (float)((const bf16*)g)[c];
    const float bv = f32 ? ((const float*)b)[c] : (float)((const bf16*)b)[c];
    hq[i] = (v[i] - mean) * rstd * gv + bv;
    am = fmaxf(am, fabsf(hq[i]));
  }
  am = wred_max(am);
  if ((tid & 63) == 0) sred[tid >> 6] = am;
  __syncthreads();
  am = fmaxf(fmaxf(sred[0], sred[1]), fmaxf(sred[2], sred[3]));
  const float cl = fmaxf(am, 1e-5f);
  const float s127 = 127.0f / cl;
#pragma unroll
  for (int i = 0; i < 8; i++) {
    float r = rintf(hq[i] * s127);
    r = fminf(fmaxf(r, -128.0f), 127.0f);
    q[(size_t)row * 2048 + tid + 256 * i] = (i8)r;
  }
  if (tid == 0) sc[row] = cl * (1.0f / 127.0f);
}

// plain per-row absmax quantize bf16 -> int8
template <int IT>
__global__ __launch_bounds__(256) void k_rowq(const bf16* __restrict__ in, i8* __restrict__ q,
                                              float* __restrict__ sc) {
  const int row = blockIdx.x, tid = threadIdx.x;
  const int C = IT * 256;
  __shared__ float sred[4];
  const bf16* xr = in + (size_t)row * C;
  float v[IT];
  float am = 0.0f;
#pragma unroll
  for (int i = 0; i < IT; i++) {
    v[i] = (float)xr[tid + 256 * i];
    am = fmaxf(am, fabsf(v[i]));
  }
  am = wred_max(am);
  if ((tid & 63) == 0) sred[tid >> 6] = am;
  __syncthreads();
  am = fmaxf(fmaxf(sred[0], sred[1]), fmaxf(sred[2], sred[3]));
  const float cl = fmaxf(am, 1e-5f);
  const float s127 = 127.0f / cl;
#pragma unroll
  for (int i = 0; i < IT; i++) {
    float r = rintf(v[i] * s127);
    r = fminf(fmaxf(r, -128.0f), 127.0f);
    q[(size_t)row * C + tid + 256 * i] = (i8)r;
  }
  if (tid == 0) sc[row] = cl * (1.0f / 127.0f);
}

// ---------------- int8 GEMM (m97 structure, K-step 64, i32 accumulate — exact) ----------------
// EPI 2: out bf16 = relu(sA[m]*cw*val)^2   (w1 -> F; direct, no split)
// EPI 4: atomicAdd i32 partial into out    (split-K; exact integer)
template <int EPI>
__global__ __launch_bounds__(256) void k_gemm(const i8* __restrict__ A, const i8* __restrict__ B,
                                              const float* __restrict__ sA,
                                              const float* __restrict__ wsum, float winv,
                                              void* __restrict__ out,
                                              int M, int N, int K, int Kc,
                                              const int* __restrict__ flag) {
  __shared__ __align__(16) i8 As[128 * 64];
  __shared__ __align__(16) i8 Bs[128 * 64];
  const int tid = threadIdx.x;
  const int lane = tid & 63;
  const int ml = lane & 15;
  const int q4 = lane >> 4;
  const int wid = tid >> 6;
  const int wM = wid >> 1;
  const int wN = wid & 1;
  const int m0 = blockIdx.y * 128;
  const int n0 = blockIdx.x * 128;

  const int r0 = tid >> 2;           // 0..63
  const int c0 = (tid & 3) * 16;     // 0,16,32,48
  const i8* Ag0 = A + (size_t)(m0 + r0) * K + c0;
  const i8* Ag1 = Ag0 + (size_t)64 * K;
  const i8* Bg0 = B + (size_t)(n0 + r0) * K + c0;
  const i8* Bg1 = Bg0 + (size_t)64 * K;
  i8* as0 = &As[wid * 1024];
  i8* as1 = &As[4096 + wid * 1024];
  i8* bs0 = &Bs[wid * 1024];
  i8* bs1 = &Bs[4096 + wid * 1024];

  v4i acc[4][4] = {};

  const int kbeg = blockIdx.z * Kc;
  const int kfin = kbeg + Kc;
  for (int k0 = kbeg; k0 < kfin; k0 += 64) {
    __syncthreads();
    glds16(Ag0 + k0, as0);
    glds16(Ag1 + k0, as1);
    glds16(Bg0 + k0, bs0);
    glds16(Bg1 + k0, bs1);
    __syncthreads();
    v4i af[4], bfr[4];
#pragma unroll
    for (int i = 0; i < 4; i++) af[i] = *(const v4i*)&As[(wM * 64 + i * 16 + ml) * 64 + q4 * 16];
#pragma unroll
    for (int j = 0; j < 4; j++) bfr[j] = *(const v4i*)&Bs[(wN * 64 + j * 16 + ml) * 64 + q4 * 16];
#pragma unroll
    for (int i = 0; i < 4; i++)
#pragma unroll
      for (int j = 0; j < 4; j++) acc[i][j] = MFMA_I8(af[i], bfr[j], acc[i][j]);
  }

  if (EPI == 4) {
    int* ob = (int*)out;
#pragma unroll
    for (int i = 0; i < 4; i++)
#pragma unroll
      for (int r = 0; r < 4; r++) {
        const int row = m0 + wM * 64 + i * 16 + q4 * 4 + r;
#pragma unroll
        for (int j = 0; j < 4; j++) {
          const int col = n0 + wN * 64 + j * 16 + ml;
          atomicAdd(ob + (size_t)row * N + col, acc[i][j][r]);
        }
      }
    return;
  }

  // EPI == 2 (direct relu^2 bf16)
  const float cw = fmaxf(wsum[0] * winv, 1e-5f);
#pragma unroll
  for (int i = 0; i < 4; i++) {
#pragma unroll
    for (int r = 0; r < 4; r++) {
      const int row = m0 + wM * 64 + i * 16 + q4 * 4 + r;
      const float sa = sA[row] * cw;
#pragma unroll
      for (int j = 0; j < 4; j++) {
        const int col = n0 + wN * 64 + j * 16 + ml;
        const float val = (float)acc[i][j][r] * sa;
        float u = fmaxf(val, 0.0f);
        ((bf16*)out)[(size_t)row * N + col] = (bf16)(u * u);
      }
    }
  }
}

// ---------------- split-K scale/residual epilogues (i32 acc in) ----------------
// MODE 0: out bf16 = acc*sA[row]*cw                     (Q, K)
// MODE 1: out f32  = resid(flag-typed) + acc*sA[row]*cw (x1)
// MODE 2: out flag-typed = x1(f32) + acc*sA[row]*cw     (final)
// MODE 3: out bf16 = acc*sA[col]*cw                     (Vt: row=d, col-scale s1[t])
template <int MODE>
__global__ __launch_bounds__(256) void k_epi(const int* __restrict__ acc, int lda, int cofs,
                                             int ncols,
                                             const float* __restrict__ sA,
                                             const float* __restrict__ wsum, float winv,
                                             const void* __restrict__ resid,
                                             void* __restrict__ out,
                                             const int* __restrict__ flag) {
  const int row = blockIdx.x, tid = threadIdx.x;
  const float cw = fmaxf(wsum[0] * winv, 1e-5f);
  const float srow = (MODE == 3) ? cw : sA[row] * cw;
  const int f32 = flag[0];
  for (int c = tid * 4; c < ncols; c += 1024) {
    const v4i a = *(const v4i*)(acc + (size_t)row * lda + cofs + c);
    float s0 = srow, s1 = srow, s2 = srow, s3 = srow;
    if (MODE == 3) {
      float4 sc = *(const float4*)(sA + c);
      s0 *= sc.x; s1 *= sc.y; s2 *= sc.z; s3 *= sc.w;
    }
    const float v0 = (float)a[0] * s0, v1 = (float)a[1] * s1;
    const float v2 = (float)a[2] * s2, v3 = (float)a[3] * s3;
    const size_t o = (size_t)row * ncols + c;
    if (MODE == 0 || MODE == 3) {
      v4bf r;
      r[0] = (bf16)v0; r[1] = (bf16)v1; r[2] = (bf16)v2; r[3] = (bf16)v3;
      *(v4bf*)((bf16*)out + o) = r;
    } else if (MODE == 1) {
      float4 rv;
      if (f32) {
        rv = *(const float4*)((const float*)resid + o);
      } else {
        const v4bf rb = *(const v4bf*)((const bf16*)resid + o);
        rv = make_float4((float)rb[0], (float)rb[1], (float)rb[2], (float)rb[3]);
      }
      *(float4*)((float*)out + o) = make_float4(rv.x + v0, rv.y + v1, rv.z + v2, rv.w + v3);
    } else {  // MODE 2
      const float4 rv = *(const float4*)((const float*)resid + o);
      const float o0 = rv.x + v0, o1 = rv.y + v1, o2 = rv.z + v2, o3 = rv.w + v3;
      if (f32) {
        *(float4*)((float*)out + o) = make_float4(o0, o1, o2, o3);
      } else {
        v4bf r;
        r[0] = (bf16)o0; r[1] = (bf16)o1; r[2] = (bf16)o2; r[3] = (bf16)o3;
        *(v4bf*)((bf16*)out + o) = r;
      }
    }
  }
}

// ---------------- MFMA flash attention (causal, GQA 32q/8kv heads, D=64) ----------------
// Swapped-operand 32x32 structure; softmax in-register; no LDS, no barriers.
// Hybrid split-KV: blockIdx.x in [0,128):
//   x <  32 : light tile t=x   (<=32 kv-blocks), direct normalized output.
//   x >= 32 : heavy tile t=32+e/3, chunk z=e%3 (<=22 kv-blocks); writes
//             unnormalized f32 O-partials + (m,l) -> merged by k_amerge. Exact.
//   (96 heavy blocks total: 32 tiles x 3 chunks; grid.x MUST be 128.)
// Defer-max (T13, THR=8): skip acc rescale while tile max stays within m+8.
__global__ __launch_bounds__(64) void k_attn(const bf16* __restrict__ Q, const bf16* __restrict__ Kb,
                                             const bf16* __restrict__ Vt, bf16* __restrict__ O,
                                             float* __restrict__ Pacc, float* __restrict__ Ml) {
  const int h = blockIdx.y;
  const int kvh = h >> 2;
  const int x = blockIdx.x;
  int t, b0, b1, z;
  if (x < 32) {
    t = x; b0 = 0; b1 = t + 1; z = 0;
  } else {
    const int e = x - 32;
    t = 32 + e / 3;
    z = e - (t - 32) * 3;
    const int nb = t + 1;
    b0 = (z * nb) / 3;
    b1 = ((z + 1) * nb) / 3;
  }
  if (t >= 64) return;  // safety: never touch rows/partials past the problem
  const int qw0 = t * 32;
  const int lane = threadIdx.x;
  const int ql = lane & 31;
  const int hi = lane >> 5;

  v8bf qf[4];
  {
    const bf16* qp = Q + (size_t)(qw0 + ql) * 2048 + h * 64 + hi * 8;
#pragma unroll
    for (int c = 0; c < 4; c++) qf[c] = *(const v8bf*)(qp + c * 16);
  }

  float m = -1e30f, l = 0.0f;
  f32x16 acc0 = {}, acc1 = {};

  const bf16* kbase = Kb + kvh * 64 + hi * 8;
  const bf16* vbase = Vt + (size_t)(kvh * 64 + ql) * 2048 + hi * 8;

  for (int kb = b0 * 32; kb < b1 * 32; kb += 32) {
    f32x16 s = {};
    {
      const bf16* kp = kbase + (size_t)(kb + ql) * 512;
#pragma unroll
      for (int c = 0; c < 4; c++) {
        const v8bf kf = *(const v8bf*)(kp + c * 16);
        s = MFMA32(kf, qf[c], s);
      }
    }
    const bool diag = (kb == qw0);
    float p[16];
    float rm = -1e30f;
#pragma unroll
    for (int r = 0; r < 16; r++) {
      float v = s[r] * 0.125f;
      const int koff = (r & 3) + ((r >> 2) << 3) + (hi << 2);
      if (diag && koff > ql) v = -1e30f;
      p[r] = v;
      rm = fmaxf(rm, v);
    }
    rm = fmaxf(rm, __shfl_xor(rm, 32));
    // defer-max: only rescale when tile max exceeds running max by > 8
    if (!__all(rm <= m + 8.0f)) {
      const float mn = fmaxf(m, rm);
      const float alpha = __expf(m - mn);
      l *= alpha;
#pragma unroll
      for (int r = 0; r < 16; r++) { acc0[r] *= alpha; acc1[r] *= alpha; }
      m = mn;
    }
    float rs = 0.0f;
#pragma unroll
    for (int r = 0; r < 16; r++) {
      p[r] = __expf(p[r] - m);
      rs += p[r];
    }
    rs += __shfl_xor(rs, 32);
    l += rs;

    unsigned int w0 = packbf(p[0], p[1]),   w2 = packbf(p[4], p[5]);
    unsigned int w1 = packbf(p[2], p[3]),   w3 = packbf(p[6], p[7]);
    unsigned int x0 = packbf(p[8], p[9]),   x2 = packbf(p[12], p[13]);
    unsigned int x1 = packbf(p[10], p[11]), x3 = packbf(p[14], p[15]);
    asm("v_permlane32_swap_b32 %0, %1" : "+v"(w0), "+v"(w2));
    asm("v_permlane32_swap_b32 %0, %1" : "+v"(w1), "+v"(w3));
    asm("v_permlane32_swap_b32 %0, %1" : "+v"(x0), "+v"(x2));
    asm("v_permlane32_swap_b32 %0, %1" : "+v"(x1), "+v"(x3));
    union BU { unsigned int u[4]; v8bf v; } B0, B1;
    B0.u[0] = w0; B0.u[1] = w1; B0.u[2] = w2; B0.u[3] = w3;
    B1.u[0] = x0; B1.u[1] = x1; B1.u[2] = x2; B1.u[3] = x3;

    const bf16* vp = vbase + kb;
    const v8bf v00 = *(const v8bf*)(vp);
    const v8bf v01 = *(const v8bf*)(vp + 16);
    const v8bf v10 = *(const v8bf*)(vp + (size_t)32 * 2048);
    const v8bf v11 = *(const v8bf*)(vp + (size_t)32 * 2048 + 16);
    acc0 = MFMA32(v00, B0.v, acc0);
    acc0 = MFMA32(v01, B1.v, acc0);
    acc1 = MFMA32(v10, B0.v, acc1);
    acc1 = MFMA32(v11, B1.v, acc1);
  }

  if (x < 32) {
    // direct normalized output
    const float inv = 1.0f / l;
    unsigned int* op = (unsigned int*)(O + (size_t)(qw0 + ql) * 2048 + h * 64);
#pragma unroll
    for (int r = 0; r < 16; r += 2) {
      const int d = (r & 3) + ((r >> 2) << 3) + (hi << 2);
      op[d >> 1] = packbf(acc0[r] * inv, acc0[r + 1] * inv);
      op[(d >> 1) + 16] = packbf(acc1[r] * inv, acc1[r + 1] * inv);
    }
  } else {
    // unnormalized f32 partials + (m,l) for merge
    float* pb = Pacc + ((size_t)((h * 32 + (t - 32)) * 3 + z)) * 2048 + ql * 64;
#pragma unroll
    for (int r = 0; r < 16; r += 2) {
      const int d = (r & 3) + ((r >> 2) << 3) + (hi << 2);
      *(float2*)(pb + d) = make_float2(acc0[r], acc0[r + 1]);
      *(float2*)(pb + 32 + d) = make_float2(acc1[r], acc1[r + 1]);
    }
    if (hi == 0) {
      float* mlp = Ml + ((size_t)((h * 32 + (t - 32)) * 3 + z)) * 64;
      mlp[ql] = m;
      mlp[32 + ql] = l;
    }
  }
}

// merge 3 chunks for heavy tiles (t=32+blockIdx.x): exact log-sum-exp combine
__global__ __launch_bounds__(256) void k_amerge(const float* __restrict__ Pacc,
                                                const float* __restrict__ Ml,
                                                bf16* __restrict__ O) {
  const int tb = blockIdx.x, h = blockIdx.y, tid = threadIdx.x;
  const int q = tid >> 3;
  const int d0 = (tid & 7) * 8;
  const size_t idx = (size_t)(h * 32 + tb) * 3;
  const float* mlp = Ml + idx * 64;
  const float m0 = mlp[q],       l0 = mlp[32 + q];
  const float m1 = mlp[64 + q],  l1 = mlp[96 + q];
  const float m2 = mlp[128 + q], l2 = mlp[160 + q];
  const float M = fmaxf(fmaxf(m0, m1), m2);
  const float w0 = __expf(m0 - M), w1 = __expf(m1 - M), w2 = __expf(m2 - M);
  const float inv = 1.0f / (w0 * l0 + w1 * l1 + w2 * l2);
  const float* p = Pacc + idx * 2048 + q * 64 + d0;
  unsigned int u[4];
#pragma unroll
  for (int j = 0; j < 8; j += 2) {
    const float a = (w0 * p[j] + w1 * p[2048 + j] + w2 * p[4096 + j]) * inv;
    const float b = (w0 * p[j + 1] + w1 * p[2048 + j + 1] + w2 * p[4096 + j + 1]) * inv;
    u[j >> 1] = packbf(a, b);
  }
  *(uint4*)((char*)O + ((size_t)((32 + tb) * 32 + q) * 2048 + h * 64 + d0) * 2) =
      make_uint4(u[0], u[1], u[2], u[3]);
}

// ---------------- launcher ----------------
// Workspace (96 MB + 64 KB), offsets from `big` (MB):
//   0-16   w1z(i8) [->FFN gemm]  ... then fq(i8) after rowq32
//   16-32  w2z(i8)
//   32-36  wqz  36-37 wkz (contiguous [2560][2048])  37-38 wvz  38-42 woz
//   42-46  xq1(i8) [->proj gemms]
//   46-66  accQK(i32) [->epis]
//   66-70  accVt(i32) [->epi3]
//   42-66  Pacc(f32, attn partials) ; 66-67 Ml      [attn->merge]
//   70-72  Kbuf  72-74 Vt  74-82 Qb                 [epis->attn]
//   82-90  Ob                                       [attn/merge->rowq]
//   42-46  oq(i8)  46-62 accO(i32)                  [rowq->wo gemm->epi1]
//   80-96  x1(f32)                                  [epi1->end]
//   74-78  xq2(i8)  42-74 Fb(bf16)                  [lnq2->gemm2->rowq32]
//   42-58  accF(i32)                                [w2 gemm->epi2]
extern "C" void kernel_launch(void* const* d_in, const int* in_sizes, int n_in, void* d_out,
                              int out_size, void* d_ws, size_t ws_size, hipStream_t stream) {
  const void* x = d_in[0];
  const void* g1 = d_in[1];
  const void* b1 = d_in[2];
  const void* g2 = d_in[3];
  const void* b2 = d_in[4];
  const void* wq = d_in[5];
  const void* wk = d_in[6];
  const void* wv = d_in[7];
  const void* wo = d_in[8];
  const void* w1 = d_in[9];
  const void* w2 = d_in[10];

  char* ws = (char*)d_ws;
  const size_t MB = 1ull << 20;
  float* wsum = (float*)ws;
  float* s1 = (float*)(ws + 8192);
  float* so = (float*)(ws + 16384);
  float* s2 = (float*)(ws + 24576);
  float* sf = (float*)(ws + 32768);
  int* flag = (int*)(ws + 40960);
  char* big = ws + 65536;

  i8* w1z = (i8*)(big);
  i8* fq  = (i8*)(big);
  i8* w2z = (i8*)(big + 16 * MB);
  i8* wqz = (i8*)(big + 32 * MB);   // [2560][2048] contiguous with wkz
  i8* wkz = (i8*)(big + 36 * MB);
  i8* wvz = (i8*)(big + 37 * MB);
  i8* woz = (i8*)(big + 38 * MB);
  i8* xq1 = (i8*)(big + 42 * MB);
  i8* oq  = xq1;
  int* accQK = (int*)(big + 46 * MB);   // [2048][2560]
  int* accVt = (int*)(big + 66 * MB);   // [512][2048]
  float* Pacc = (float*)(big + 42 * MB);  // 32x32x3 x 32x64 f32 = 24 MB
  float* Ml   = (float*)(big + 66 * MB);  // 32x32x3 x 64 f32
  bf16* Kbuf = (bf16*)(big + 70 * MB);
  bf16* Vt   = (bf16*)(big + 72 * MB);
  bf16* Qb   = (bf16*)(big + 74 * MB);
  bf16* Ob   = (bf16*)(big + 82 * MB);
  int* accO  = (int*)(big + 46 * MB);   // [2048][2048]
  float* x1  = (float*)(big + 80 * MB);
  i8* xq2 = (i8*)(big + 74 * MB);
  bf16* Fb   = (bf16*)(big + 42 * MB);  // [2048][8192]
  int* accF  = (int*)(big + 42 * MB);   // [2048][2048]

  const float invD2 = 1.0f / 4194304.0f;
  const float invKV = 1.0f / 1048576.0f;
  const float invF = 1.0f / 16777216.0f;

  k_sniff<<<1, 64, 0, stream>>>((const unsigned short*)x, flag);
  k_zero<<<1, 64, 0, stream>>>(wsum, 8);
  // zero accQK+accVt (contiguous 24MB @46-70)
  k_zerof<<<6144, 256, 0, stream>>>((float4*)accQK);

  k_abssum<<<512, 256, 0, stream>>>(wq, 2048 * 2048, flag, wsum + 0);
  k_abssum<<<512, 256, 0, stream>>>(wk, 512 * 2048, flag, wsum + 1);
  k_abssum<<<512, 256, 0, stream>>>(wv, 512 * 2048, flag, wsum + 2);
  k_abssum<<<512, 256, 0, stream>>>(wo, 2048 * 2048, flag, wsum + 3);
  k_abssum<<<512, 256, 0, stream>>>(w1, 8192 * 2048, flag, wsum + 4);
  k_abssum<<<512, 256, 0, stream>>>(w2, 2048 * 8192, flag, wsum + 5);
  k_wquant<<<2048, 256, 0, stream>>>(wq, wqz, wsum + 0, invD2, flag);
  k_wquant<<<512, 256, 0, stream>>>(wk, wkz, wsum + 1, invKV, flag);
  k_wquant<<<512, 256, 0, stream>>>(wv, wvz, wsum + 2, invKV, flag);
  k_wquant<<<2048, 256, 0, stream>>>(wo, woz, wsum + 3, invD2, flag);
  k_wquant<<<8192, 256, 0, stream>>>(w1, w1z, wsum + 4, invF, flag);
  k_wquant<<<8192, 256, 0, stream>>>(w2, w2z, wsum + 5, invF, flag);

  // ---- attention sublayer ----
  k_lnq<false><<<2048, 256, 0, stream>>>(x, g1, b1, xq1, s1, flag);
  // fused Q+K projection: B = [wqz;wkz] (2560 rows), split-K x4 -> accQK
  k_gemm<4><<<dim3(20, 16, 4), 256, 0, stream>>>(xq1, wqz, s1, wsum + 0, invD2, accQK,
                                                 2048, 2560, 2048, 512, flag);
  // V^T directly: C[d][t] = wvz[d].xq1[t], split-K x4 -> accVt
  k_gemm<4><<<dim3(16, 4, 4), 256, 0, stream>>>(wvz, xq1, s1, wsum + 2, invKV, accVt,
                                                512, 2048, 2048, 512, flag);
  k_epi<0><<<2048, 256, 0, stream>>>(accQK, 2560, 0, 2048, s1, wsum + 0, invD2, nullptr, Qb, flag);
  k_epi<0><<<2048, 256, 0, stream>>>(accQK, 2560, 2048, 512, s1, wsum + 1, invKV, nullptr, Kbuf, flag);
  k_epi<3><<<512, 256, 0, stream>>>(accVt, 2048, 0, 2048, s1, wsum + 2, invKV, nullptr, Vt, flag);
  k_attn<<<dim3(128, 32), 64, 0, stream>>>(Qb, Kbuf, Vt, Ob, Pacc, Ml);
  k_amerge<<<dim3(32, 32), 256, 0, stream>>>(Pacc, Ml, Ob);
  k_rowq<8><<<2048, 256, 0, stream>>>(Ob, oq, so);
  k_zerof<<<4096, 256, 0, stream>>>((float4*)accO);  // after merge read Pacc
  k_gemm<4><<<dim3(16, 16, 4), 256, 0, stream>>>(oq, woz, so, wsum + 3, invD2, accO,
                                                 2048, 2048, 2048, 512, flag);
  k_epi<1><<<2048, 256, 0, stream>>>(accO, 2048, 0, 2048, so, wsum + 3, invD2, x, x1, flag);

  // ---- FFN sublayer ----
  k_lnq<true><<<2048, 256, 0, stream>>>(x1, g2, b2, xq2, s2, flag);
  k_gemm<2><<<dim3(64, 16, 1), 256, 0, stream>>>(xq2, w1z, s2, wsum + 4, invF, Fb,
                                                 2048, 8192, 2048, 2048, flag);
  k_rowq<32><<<2048, 256, 0, stream>>>(Fb, fq, sf);  // fq overwrites dead w1z
  k_zerof<<<4096, 256, 0, stream>>>((float4*)accF);  // after rowq read Fb
  k_gemm<4><<<dim3(16, 16, 4), 256, 0, stream>>>(fq, w2z, sf, wsum + 5, invF, accF,
                                                 2048, 2048, 8192, 2048, flag);
  k_epi<2><<<2048, 256, 0, stream>>>(accF, 2048, 0, 2048, sf, wsum + 5, invF, x1, d_out, flag);
}

// Round 6
// 662.679 us; speedup vs baseline: 1.1373x; 1.1373x over previous
//
#include <hip/hip_runtime.h>
#include <hip/hip_bf16.h>
#include <stdint.h>

typedef __bf16 bf16;
typedef signed char i8;
typedef __bf16 v8bf __attribute__((ext_vector_type(8)));
typedef __bf16 v4bf __attribute__((ext_vector_type(4)));
typedef signed char v8i8 __attribute__((ext_vector_type(8)));
typedef int    v4i  __attribute__((ext_vector_type(4)));
typedef float  f32x16 __attribute__((ext_vector_type(16)));

#define MFMA32(a,b,c)   __builtin_amdgcn_mfma_f32_32x32x16_bf16((a),(b),(c),0,0,0)
#define MFMA_I8(a,b,c)  __builtin_amdgcn_mfma_i32_16x16x64_i8((a),(b),(c),0,0,0)

#define INV_D2 (1.0f / 4194304.0f)
#define INV_KV (1.0f / 1048576.0f)
#define INV_F  (1.0f / 16777216.0f)

__device__ __forceinline__ void glds16(const void* g, void* l) {
  __builtin_amdgcn_global_load_lds(
      (const __attribute__((address_space(1))) void*)g,
      (__attribute__((address_space(3))) void*)l, 16, 0, 0);
}

__device__ __forceinline__ float wred_sum(float v) {
#pragma unroll
  for (int o = 32; o; o >>= 1) v += __shfl_xor(v, o);
  return v;
}
__device__ __forceinline__ float wred_max(float v) {
#pragma unroll
  for (int o = 32; o; o >>= 1) v = fmaxf(v, __shfl_xor(v, o));
  return v;
}

__device__ __forceinline__ unsigned int packbf(float a, float b) {
  union { bf16 h[2]; unsigned int u; } x;
  x.h[0] = (bf16)a; x.h[1] = (bf16)b;
  return x.u;
}

// ---------------- dtype sniffer (inputs turned out fp32; keep robust) ----------------
__global__ void k_sniff(const unsigned short* __restrict__ x, int* __restrict__ flag) {
  int cnt = 0;
  for (int i = threadIdx.x; i < 2048; i += 64) {
    const unsigned short u = x[i];
    const int e = (u >> 7) & 0xFF;
    if (u == 0 || (e >= 100 && e <= 140)) cnt++;
  }
#pragma unroll
  for (int o = 32; o; o >>= 1) cnt += __shfl_xor(cnt, o);
  if (threadIdx.x == 0) flag[0] = (cnt >= 1844) ? 0 : 1;  // 0 = bf16, 1 = f32
}

// ---------------- small utility kernels ----------------

__global__ void k_zero(float* p, int n) {
  int i = threadIdx.x;
  if (i < n) p[i] = 0.0f;
}

// zero a float4-aligned buffer; grid = bytes/16/256
__global__ __launch_bounds__(256) void k_zerof(float4* __restrict__ p) {
  p[(size_t)blockIdx.x * 256 + threadIdx.x] = make_float4(0.f, 0.f, 0.f, 0.f);
}

// fused abs-sum over all 6 weights; segments in 64K-element units:
// wq 64 | wk 16 | wv 16 | wo 64 | w1 256 | w2 256  => grid = 672 blocks
__global__ __launch_bounds__(256) void k_abssum6(const void* __restrict__ p0, const void* __restrict__ p1,
                                                 const void* __restrict__ p2, const void* __restrict__ p3,
                                                 const void* __restrict__ p4, const void* __restrict__ p5,
                                                 const int* __restrict__ flag, float* __restrict__ out) {
  const int b = blockIdx.x, tid = threadIdx.x;
  const void* w; int seg, base;
  if (b < 64)       { w = p0; seg = 0; base = b; }
  else if (b < 80)  { w = p1; seg = 1; base = b - 64; }
  else if (b < 96)  { w = p2; seg = 2; base = b - 80; }
  else if (b < 160) { w = p3; seg = 3; base = b - 96; }
  else if (b < 416) { w = p4; seg = 4; base = b - 160; }
  else              { w = p5; seg = 5; base = b - 416; }
  const int f32 = flag[0];
  __shared__ float sred[4];
  float s = 0.0f;
  if (f32) {
    const float4* p = (const float4*)w + (size_t)base * 16384;
#pragma unroll 4
    for (int i = 0; i < 64; i++) {
      float4 a = p[i * 256 + tid];
      s += fabsf(a.x) + fabsf(a.y) + fabsf(a.z) + fabsf(a.w);
    }
  } else {
    const v8bf* p = (const v8bf*)w + (size_t)base * 8192;
#pragma unroll 4
    for (int i = 0; i < 32; i++) {
      v8bf v = p[i * 256 + tid];
#pragma unroll
      for (int j = 0; j < 8; j++) s += fabsf((float)v[j]);
    }
  }
  s = wred_sum(s);
  if ((tid & 63) == 0) sred[tid >> 6] = s;
  __syncthreads();
  if (tid == 0) atomicAdd(out + seg, sred[0] + sred[1] + sred[2] + sred[3]);
}

// fused ternary weight quant -> int8 for all 6 weights; 2048 elems/block:
// wq 2048 | wk 512 | wv 512 | wo 2048 | w1 8192 | w2 8192 => grid = 21504
__global__ __launch_bounds__(256) void k_wquant6(const void* __restrict__ p0, const void* __restrict__ p1,
                                                 const void* __restrict__ p2, const void* __restrict__ p3,
                                                 const void* __restrict__ p4, const void* __restrict__ p5,
                                                 i8* __restrict__ d0, i8* __restrict__ d1,
                                                 i8* __restrict__ d2, i8* __restrict__ d3,
                                                 i8* __restrict__ d4, i8* __restrict__ d5,
                                                 const float* __restrict__ wsum,
                                                 const int* __restrict__ flag) {
  const int b = blockIdx.x;
  const void* w; i8* o; int seg, base; float invn;
  if (b < 2048)       { w = p0; o = d0; seg = 0; base = b;         invn = INV_D2; }
  else if (b < 2560)  { w = p1; o = d1; seg = 1; base = b - 2048;  invn = INV_KV; }
  else if (b < 3072)  { w = p2; o = d2; seg = 2; base = b - 2560;  invn = INV_KV; }
  else if (b < 5120)  { w = p3; o = d3; seg = 3; base = b - 3072;  invn = INV_D2; }
  else if (b < 13312) { w = p4; o = d4; seg = 4; base = b - 5120;  invn = INV_F; }
  else                { w = p5; o = d5; seg = 5; base = b - 13312; invn = INV_F; }
  const int gid = base * 256 + threadIdx.x;
  const int i = gid * 8;
  const float ws = 1.0f / fmaxf(wsum[seg] * invn, 1e-5f);
  const int f32 = flag[0];
  float v[8];
  if (f32) {
    float4 a = ((const float4*)w)[gid * 2];
    float4 b4 = ((const float4*)w)[gid * 2 + 1];
    v[0] = a.x; v[1] = a.y; v[2] = a.z; v[3] = a.w;
    v[4] = b4.x; v[5] = b4.y; v[6] = b4.z; v[7] = b4.w;
  } else {
    v8bf t = *(const v8bf*)((const bf16*)w + i);
#pragma unroll
    for (int j = 0; j < 8; j++) v[j] = (float)t[j];
  }
  v8i8 r;
#pragma unroll
  for (int j = 0; j < 8; j++) {
    float t = rintf(v[j] * ws);
    r[j] = (i8)fminf(fmaxf(t, -1.0f), 1.0f);
  }
  *(v8i8*)(o + i) = r;
}

// LayerNorm + per-row absmax quantize -> int8.
template <bool XINT>
__global__ __launch_bounds__(256) void k_lnq(const void* __restrict__ x, const void* __restrict__ g,
                                             const void* __restrict__ b, i8* __restrict__ q,
                                             float* __restrict__ sc, const int* __restrict__ flag) {
  const int row = blockIdx.x, tid = threadIdx.x;
  const int f32 = flag[0];
  __shared__ float sred[4];
  float v[8];
#pragma unroll
  for (int i = 0; i < 8; i++) {
    const size_t idx = (size_t)row * 2048 + tid + 256 * i;
    if (XINT)      v[i] = ((const float*)x)[idx];
    else if (f32)  v[i] = ((const float*)x)[idx];
    else           v[i] = (float)((const bf16*)x)[idx];
  }
  float s = 0.0f;
#pragma unroll
  for (int i = 0; i < 8; i++) s += v[i];
  s = wred_sum(s);
  if ((tid & 63) == 0) sred[tid >> 6] = s;
  __syncthreads();
  const float mean = (sred[0] + sred[1] + sred[2] + sred[3]) * (1.0f / 2048.0f);
  __syncthreads();
  float vs = 0.0f;
#pragma unroll
  for (int i = 0; i < 8; i++) { float d = v[i] - mean; vs += d * d; }
  vs = wred_sum(vs);
  if ((tid & 63) == 0) sred[tid >> 6] = vs;
  __syncthreads();
  const float rstd = rsqrtf((sred[0] + sred[1] + sred[2] + sred[3]) * (1.0f / 2048.0f) + 1e-6f);
  __syncthreads();
  float hq[8];
  float am = 0.0f;
#pragma unroll
  for (int i = 0; i < 8; i++) {
    const int c = tid + 256 * i;
    const float gv = f32 ? ((const float*)g)[c] : (float)((const bf16*)g)[c];
    const float bv = f32 ? ((const float*)b)[c] : (float)((const bf16*)b)[c];
    hq[i] = (v[i] - mean) * rstd * gv + bv;
    am = fmaxf(am, fabsf(hq[i]));
  }
  am = wred_max(am);
  if ((tid & 63) == 0) sred[tid >> 6] = am;
  __syncthreads();
  am = fmaxf(fmaxf(sred[0], sred[1]), fmaxf(sred[2], sred[3]));
  const float cl = fmaxf(am, 1e-5f);
  const float s127 = 127.0f / cl;
#pragma unroll
  for (int i = 0; i < 8; i++) {
    float r = rintf(hq[i] * s127);
    r = fminf(fmaxf(r, -128.0f), 127.0f);
    q[(size_t)row * 2048 + tid + 256 * i] = (i8)r;
  }
  if (tid == 0) sc[row] = cl * (1.0f / 127.0f);
}

// plain per-row absmax quantize bf16 -> int8
template <int IT>
__global__ __launch_bounds__(256) void k_rowq(const bf16* __restrict__ in, i8* __restrict__ q,
                                              float* __restrict__ sc) {
  const int row = blockIdx.x, tid = threadIdx.x;
  const int C = IT * 256;
  __shared__ float sred[4];
  const bf16* xr = in + (size_t)row * C;
  float v[IT];
  float am = 0.0f;
#pragma unroll
  for (int i = 0; i < IT; i++) {
    v[i] = (float)xr[tid + 256 * i];
    am = fmaxf(am, fabsf(v[i]));
  }
  am = wred_max(am);
  if ((tid & 63) == 0) sred[tid >> 6] = am;
  __syncthreads();
  am = fmaxf(fmaxf(sred[0], sred[1]), fmaxf(sred[2], sred[3]));
  const float cl = fmaxf(am, 1e-5f);
  const float s127 = 127.0f / cl;
#pragma unroll
  for (int i = 0; i < IT; i++) {
    float r = rintf(v[i] * s127);
    r = fminf(fmaxf(r, -128.0f), 127.0f);
    q[(size_t)row * C + tid + 256 * i] = (i8)r;
  }
  if (tid == 0) sc[row] = cl * (1.0f / 127.0f);
}

// ---------------- int8 GEMM: double-buffered LDS, 1 barrier/K-step (T3-minimum) ----------------
// Stage K-tile t+1 into buf^1 BEFORE compute of buf; single __syncthreads at the
// end of each step (its implicit vmcnt(0)/lgkmcnt(0) drain provides the ordering:
// staging of buf[c^1] is safe since its readers finished before the previous
// barrier; readers of buf[c] see data staged+drained the step before).
// EPI 2: out bf16 = relu(sA[m]*cw*val)^2   (w1 -> F; direct, no split)
// EPI 4: atomicAdd i32 partial into out    (split-K; exact integer)
template <int EPI>
__global__ __launch_bounds__(256) void k_gemm(const i8* __restrict__ A, const i8* __restrict__ B,
                                              const float* __restrict__ sA,
                                              const float* __restrict__ wsum, float winv,
                                              void* __restrict__ out,
                                              int M, int N, int K, int Kc,
                                              const int* __restrict__ flag) {
  __shared__ __align__(16) i8 As[2][128 * 64];
  __shared__ __align__(16) i8 Bs[2][128 * 64];
  const int tid = threadIdx.x;
  const int lane = tid & 63;
  const int ml = lane & 15;
  const int q4 = lane >> 4;
  const int wid = tid >> 6;
  const int wM = wid >> 1;
  const int wN = wid & 1;
  const int m0 = blockIdx.y * 128;
  const int n0 = blockIdx.x * 128;

  const int r0 = tid >> 2;           // 0..63
  const int c0 = (tid & 3) * 16;     // 0,16,32,48
  const i8* Ag0 = A + (size_t)(m0 + r0) * K + c0;
  const i8* Ag1 = Ag0 + (size_t)64 * K;
  const i8* Bg0 = B + (size_t)(n0 + r0) * K + c0;
  const i8* Bg1 = Bg0 + (size_t)64 * K;
  const int l0 = wid * 1024;         // lane l of wave w -> wavebase + l*16B
  const int l1 = 4096 + wid * 1024;

  v4i acc[4][4] = {};

  const int kbeg = blockIdx.z * Kc;
  const int kfin = kbeg + Kc;
  // prologue: stage first tile into buffer 0
  glds16(Ag0 + kbeg, &As[0][l0]);
  glds16(Ag1 + kbeg, &As[0][l1]);
  glds16(Bg0 + kbeg, &Bs[0][l0]);
  glds16(Bg1 + kbeg, &Bs[0][l1]);
  __syncthreads();
  int cb = 0;
  for (int k0 = kbeg; k0 < kfin; k0 += 64) {
    const int kn = k0 + 64;
    if (kn < kfin) {  // issue next-tile staging before compute (hides latency)
      glds16(Ag0 + kn, &As[cb ^ 1][l0]);
      glds16(Ag1 + kn, &As[cb ^ 1][l1]);
      glds16(Bg0 + kn, &Bs[cb ^ 1][l0]);
      glds16(Bg1 + kn, &Bs[cb ^ 1][l1]);
    }
    v4i af[4], bfr[4];
#pragma unroll
    for (int i = 0; i < 4; i++) af[i] = *(const v4i*)&As[cb][(wM * 64 + i * 16 + ml) * 64 + q4 * 16];
#pragma unroll
    for (int j = 0; j < 4; j++) bfr[j] = *(const v4i*)&Bs[cb][(wN * 64 + j * 16 + ml) * 64 + q4 * 16];
#pragma unroll
    for (int i = 0; i < 4; i++)
#pragma unroll
      for (int j = 0; j < 4; j++) acc[i][j] = MFMA_I8(af[i], bfr[j], acc[i][j]);
    __syncthreads();  // drains this wave's vmem (staging) + all waves' reads
    cb ^= 1;
  }

  if (EPI == 4) {
    int* ob = (int*)out;
#pragma unroll
    for (int i = 0; i < 4; i++)
#pragma unroll
      for (int r = 0; r < 4; r++) {
        const int row = m0 + wM * 64 + i * 16 + q4 * 4 + r;
#pragma unroll
        for (int j = 0; j < 4; j++) {
          const int col = n0 + wN * 64 + j * 16 + ml;
          atomicAdd(ob + (size_t)row * N + col, acc[i][j][r]);
        }
      }
    return;
  }

  // EPI == 2 (direct relu^2 bf16)
  const float cw = fmaxf(wsum[0] * winv, 1e-5f);
#pragma unroll
  for (int i = 0; i < 4; i++) {
#pragma unroll
    for (int r = 0; r < 4; r++) {
      const int row = m0 + wM * 64 + i * 16 + q4 * 4 + r;
      const float sa = sA[row] * cw;
#pragma unroll
      for (int j = 0; j < 4; j++) {
        const int col = n0 + wN * 64 + j * 16 + ml;
        const float val = (float)acc[i][j][r] * sa;
        float u = fmaxf(val, 0.0f);
        ((bf16*)out)[(size_t)row * N + col] = (bf16)(u * u);
      }
    }
  }
}

// ---------------- split-K scale/residual epilogues (i32 acc in) ----------------
// MODE 0: out bf16 = acc*sA[row]*cw                     (Q, K)
// MODE 1: out f32  = resid(flag-typed) + acc*sA[row]*cw (x1)
// MODE 2: out flag-typed = x1(f32) + acc*sA[row]*cw     (final)
// MODE 3: out bf16 = acc*sA[col]*cw                     (Vt: row=d, col-scale s1[t])
template <int MODE>
__global__ __launch_bounds__(256) void k_epi(const int* __restrict__ acc, int lda, int cofs,
                                             int ncols,
                                             const float* __restrict__ sA,
                                             const float* __restrict__ wsum, float winv,
                                             const void* __restrict__ resid,
                                             void* __restrict__ out,
                                             const int* __restrict__ flag) {
  const int row = blockIdx.x, tid = threadIdx.x;
  const float cw = fmaxf(wsum[0] * winv, 1e-5f);
  const float srow = (MODE == 3) ? cw : sA[row] * cw;
  const int f32 = flag[0];
  for (int c = tid * 4; c < ncols; c += 1024) {
    const v4i a = *(const v4i*)(acc + (size_t)row * lda + cofs + c);
    float s0 = srow, s1 = srow, s2 = srow, s3 = srow;
    if (MODE == 3) {
      float4 sc = *(const float4*)(sA + c);
      s0 *= sc.x; s1 *= sc.y; s2 *= sc.z; s3 *= sc.w;
    }
    const float v0 = (float)a[0] * s0, v1 = (float)a[1] * s1;
    const float v2 = (float)a[2] * s2, v3 = (float)a[3] * s3;
    const size_t o = (size_t)row * ncols + c;
    if (MODE == 0 || MODE == 3) {
      v4bf r;
      r[0] = (bf16)v0; r[1] = (bf16)v1; r[2] = (bf16)v2; r[3] = (bf16)v3;
      *(v4bf*)((bf16*)out + o) = r;
    } else if (MODE == 1) {
      float4 rv;
      if (f32) {
        rv = *(const float4*)((const float*)resid + o);
      } else {
        const v4bf rb = *(const v4bf*)((const bf16*)resid + o);
        rv = make_float4((float)rb[0], (float)rb[1], (float)rb[2], (float)rb[3]);
      }
      *(float4*)((float*)out + o) = make_float4(rv.x + v0, rv.y + v1, rv.z + v2, rv.w + v3);
    } else {  // MODE 2
      const float4 rv = *(const float4*)((const float*)resid + o);
      const float o0 = rv.x + v0, o1 = rv.y + v1, o2 = rv.z + v2, o3 = rv.w + v3;
      if (f32) {
        *(float4*)((float*)out + o) = make_float4(o0, o1, o2, o3);
      } else {
        v4bf r;
        r[0] = (bf16)o0; r[1] = (bf16)o1; r[2] = (bf16)o2; r[3] = (bf16)o3;
        *(v4bf*)((bf16*)out + o) = r;
      }
    }
  }
}

// ---------------- MFMA flash attention (causal, GQA 32q/8kv heads, D=64) ----------------
// Round-2 form (93 us measured): swapped-operand 32x32, softmax in-register,
// no LDS, no barriers; grid (64,32), balanced q-tile swizzle. Split-KV variant
// REVERTED: it raised co-resident working set past per-XCD L2 -> latency-bound
// (r5: FETCH +42%, per-wave stall ~4x, 129 us).
__global__ __launch_bounds__(64) void k_attn(const bf16* __restrict__ Q, const bf16* __restrict__ Kb,
                                             const bf16* __restrict__ Vt, bf16* __restrict__ O) {
  const int h = blockIdx.y;
  const int kvh = h >> 2;
  const int t = (blockIdx.x + ((h >> 2) << 3)) & 63;  // balanced q-tile swizzle
  const int qw0 = t * 32;
  const int lane = threadIdx.x;
  const int ql = lane & 31;
  const int hi = lane >> 5;

  v8bf qf[4];
  {
    const bf16* qp = Q + (size_t)(qw0 + ql) * 2048 + h * 64 + hi * 8;
#pragma unroll
    for (int c = 0; c < 4; c++) qf[c] = *(const v8bf*)(qp + c * 16);
  }

  float m = -1e30f, l = 0.0f;
  f32x16 acc0 = {}, acc1 = {};

  const bf16* kbase = Kb + kvh * 64 + hi * 8;
  const bf16* vbase = Vt + (size_t)(kvh * 64 + ql) * 2048 + hi * 8;

  for (int kb = 0; kb <= qw0; kb += 32) {
    f32x16 s = {};
    {
      const bf16* kp = kbase + (size_t)(kb + ql) * 512;
#pragma unroll
      for (int c = 0; c < 4; c++) {
        const v8bf kf = *(const v8bf*)(kp + c * 16);
        s = MFMA32(kf, qf[c], s);
      }
    }
    const bool diag = (kb == qw0);
    float p[16];
    float rm = -1e30f;
#pragma unroll
    for (int r = 0; r < 16; r++) {
      float v = s[r] * 0.125f;
      const int koff = (r & 3) + ((r >> 2) << 3) + (hi << 2);
      if (diag && koff > ql) v = -1e30f;
      p[r] = v;
      rm = fmaxf(rm, v);
    }
    rm = fmaxf(rm, __shfl_xor(rm, 32));
    const float mn = fmaxf(m, rm);
    const float alpha = __expf(m - mn);
    m = mn;
    float rs = 0.0f;
#pragma unroll
    for (int r = 0; r < 16; r++) {
      p[r] = __expf(p[r] - mn);
      rs += p[r];
    }
    rs += __shfl_xor(rs, 32);
    l = l * alpha + rs;
#pragma unroll
    for (int r = 0; r < 16; r++) { acc0[r] *= alpha; acc1[r] *= alpha; }

    unsigned int w0 = packbf(p[0], p[1]),   w2 = packbf(p[4], p[5]);
    unsigned int w1 = packbf(p[2], p[3]),   w3 = packbf(p[6], p[7]);
    unsigned int x0 = packbf(p[8], p[9]),   x2 = packbf(p[12], p[13]);
    unsigned int x1 = packbf(p[10], p[11]), x3 = packbf(p[14], p[15]);
    asm("v_permlane32_swap_b32 %0, %1" : "+v"(w0), "+v"(w2));
    asm("v_permlane32_swap_b32 %0, %1" : "+v"(w1), "+v"(w3));
    asm("v_permlane32_swap_b32 %0, %1" : "+v"(x0), "+v"(x2));
    asm("v_permlane32_swap_b32 %0, %1" : "+v"(x1), "+v"(x3));
    union BU { unsigned int u[4]; v8bf v; } B0, B1;
    B0.u[0] = w0; B0.u[1] = w1; B0.u[2] = w2; B0.u[3] = w3;
    B1.u[0] = x0; B1.u[1] = x1; B1.u[2] = x2; B1.u[3] = x3;

    const bf16* vp = vbase + kb;
    const v8bf v00 = *(const v8bf*)(vp);
    const v8bf v01 = *(const v8bf*)(vp + 16);
    const v8bf v10 = *(const v8bf*)(vp + (size_t)32 * 2048);
    const v8bf v11 = *(const v8bf*)(vp + (size_t)32 * 2048 + 16);
    acc0 = MFMA32(v00, B0.v, acc0);
    acc0 = MFMA32(v01, B1.v, acc0);
    acc1 = MFMA32(v10, B0.v, acc1);
    acc1 = MFMA32(v11, B1.v, acc1);
  }

  const float inv = 1.0f / l;
  unsigned int* op = (unsigned int*)(O + (size_t)(qw0 + ql) * 2048 + h * 64);
#pragma unroll
  for (int r = 0; r < 16; r += 2) {
    const int d = (r & 3) + ((r >> 2) << 3) + (hi << 2);
    op[d >> 1] = packbf(acc0[r] * inv, acc0[r + 1] * inv);
    op[(d >> 1) + 16] = packbf(acc1[r] * inv, acc1[r + 1] * inv);
  }
}

// ---------------- launcher ----------------
// Workspace (96 MB + 64 KB), offsets from `big` (MB):
//   0-16   w1z(i8) [->FFN gemm]  ... then fq(i8) after rowq32
//   16-32  w2z(i8)
//   32-36  wqz  36-37 wkz (contiguous [2560][2048])  37-38 wvz  38-42 woz
//   42-46  xq1(i8) [->proj gemms]   ... then oq(i8) after rowq8
//   46-66  accQK(i32) [->epis]      ... then accO(i32) [wo gemm->epi1]
//   66-70  accVt(i32) [->epi3]
//   70-72  Kbuf  72-74 Vt  74-82 Qb [epis->attn]
//   82-90  Ob                       [attn->rowq8]
//   80-96  x1(f32)                  [epi1->end; Qb/Ob dead by then]
//   74-78  xq2(i8)  42-74 Fb(bf16)  [lnq2->gemm2->rowq32]
//   42-58  accF(i32)                [w2 gemm->epi2]
extern "C" void kernel_launch(void* const* d_in, const int* in_sizes, int n_in, void* d_out,
                              int out_size, void* d_ws, size_t ws_size, hipStream_t stream) {
  const void* x = d_in[0];
  const void* g1 = d_in[1];
  const void* b1 = d_in[2];
  const void* g2 = d_in[3];
  const void* b2 = d_in[4];
  const void* wq = d_in[5];
  const void* wk = d_in[6];
  const void* wv = d_in[7];
  const void* wo = d_in[8];
  const void* w1 = d_in[9];
  const void* w2 = d_in[10];

  char* ws = (char*)d_ws;
  const size_t MB = 1ull << 20;
  float* wsum = (float*)ws;
  float* s1 = (float*)(ws + 8192);
  float* so = (float*)(ws + 16384);
  float* s2 = (float*)(ws + 24576);
  float* sf = (float*)(ws + 32768);
  int* flag = (int*)(ws + 40960);
  char* big = ws + 65536;

  i8* w1z = (i8*)(big);
  i8* fq  = (i8*)(big);
  i8* w2z = (i8*)(big + 16 * MB);
  i8* wqz = (i8*)(big + 32 * MB);   // [2560][2048] contiguous with wkz
  i8* wkz = (i8*)(big + 36 * MB);
  i8* wvz = (i8*)(big + 37 * MB);
  i8* woz = (i8*)(big + 38 * MB);
  i8* xq1 = (i8*)(big + 42 * MB);
  i8* oq  = xq1;
  int* accQK = (int*)(big + 46 * MB);   // [2048][2560]
  int* accVt = (int*)(big + 66 * MB);   // [512][2048]
  bf16* Kbuf = (bf16*)(big + 70 * MB);
  bf16* Vt   = (bf16*)(big + 72 * MB);
  bf16* Qb   = (bf16*)(big + 74 * MB);
  bf16* Ob   = (bf16*)(big + 82 * MB);
  int* accO  = (int*)(big + 46 * MB);   // [2048][2048]
  float* x1  = (float*)(big + 80 * MB);
  i8* xq2 = (i8*)(big + 74 * MB);
  bf16* Fb   = (bf16*)(big + 42 * MB);  // [2048][8192]
  int* accF  = (int*)(big + 42 * MB);   // [2048][2048]

  k_sniff<<<1, 64, 0, stream>>>((const unsigned short*)x, flag);
  k_zero<<<1, 64, 0, stream>>>(wsum, 8);
  // zero accQK+accVt (contiguous 24MB @46-70)
  k_zerof<<<6144, 256, 0, stream>>>((float4*)accQK);

  k_abssum6<<<672, 256, 0, stream>>>(wq, wk, wv, wo, w1, w2, flag, wsum);
  k_wquant6<<<21504, 256, 0, stream>>>(wq, wk, wv, wo, w1, w2,
                                       wqz, wkz, wvz, woz, w1z, w2z, wsum, flag);

  // ---- attention sublayer ----
  k_lnq<false><<<2048, 256, 0, stream>>>(x, g1, b1, xq1, s1, flag);
  // fused Q+K projection: B = [wqz;wkz] (2560 rows), split-K x4 -> accQK
  k_gemm<4><<<dim3(20, 16, 4), 256, 0, stream>>>(xq1, wqz, s1, wsum + 0, INV_D2, accQK,
                                                 2048, 2560, 2048, 512, flag);
  // V^T directly: C[d][t] = wvz[d].xq1[t], split-K x4 -> accVt
  k_gemm<4><<<dim3(16, 4, 4), 256, 0, stream>>>(wvz, xq1, s1, wsum + 2, INV_KV, accVt,
                                                512, 2048, 2048, 512, flag);
  k_epi<0><<<2048, 256, 0, stream>>>(accQK, 2560, 0, 2048, s1, wsum + 0, INV_D2, nullptr, Qb, flag);
  k_epi<0><<<2048, 256, 0, stream>>>(accQK, 2560, 2048, 512, s1, wsum + 1, INV_KV, nullptr, Kbuf, flag);
  k_epi<3><<<512, 256, 0, stream>>>(accVt, 2048, 0, 2048, s1, wsum + 2, INV_KV, nullptr, Vt, flag);
  k_attn<<<dim3(64, 32), 64, 0, stream>>>(Qb, Kbuf, Vt, Ob);
  k_rowq<8><<<2048, 256, 0, stream>>>(Ob, oq, so);
  k_zerof<<<4096, 256, 0, stream>>>((float4*)accO);  // after epis read accQK
  k_gemm<4><<<dim3(16, 16, 4), 256, 0, stream>>>(oq, woz, so, wsum + 3, INV_D2, accO,
                                                 2048, 2048, 2048, 512, flag);
  k_epi<1><<<2048, 256, 0, stream>>>(accO, 2048, 0, 2048, so, wsum + 3, INV_D2, x, x1, flag);

  // ---- FFN sublayer ----
  k_lnq<true><<<2048, 256, 0, stream>>>(x1, g2, b2, xq2, s2, flag);
  k_gemm<2><<<dim3(64, 16, 1), 256, 0, stream>>>(xq2, w1z, s2, wsum + 4, INV_F, Fb,
                                                 2048, 8192, 2048, 2048, flag);
  k_rowq<32><<<2048, 256, 0, stream>>>(Fb, fq, sf);  // fq overwrites dead w1z
  k_zerof<<<4096, 256, 0, stream>>>((float4*)accF);  // after rowq read Fb
  k_gemm<4><<<dim3(16, 16, 4), 256, 0, stream>>>(fq, w2z, sf, wsum + 5, INV_F, accF,
                                                 2048, 2048, 8192, 2048, flag);
  k_epi<2><<<2048, 256, 0, stream>>>(accF, 2048, 0, 2048, sf, wsum + 5, INV_F, x1, d_out, flag);
}

// Round 7
// 660.141 us; speedup vs baseline: 1.1417x; 1.0038x over previous
//
#include <hip/hip_runtime.h>
#include <hip/hip_bf16.h>
#include <stdint.h>

typedef __bf16 bf16;
typedef signed char i8;
typedef __bf16 v8bf __attribute__((ext_vector_type(8)));
typedef __bf16 v4bf __attribute__((ext_vector_type(4)));
typedef signed char v8i8 __attribute__((ext_vector_type(8)));
typedef int    v4i  __attribute__((ext_vector_type(4)));
typedef float  f32x16 __attribute__((ext_vector_type(16)));

#define MFMA32(a,b,c)   __builtin_amdgcn_mfma_f32_32x32x16_bf16((a),(b),(c),0,0,0)
#define MFMA_I8(a,b,c)  __builtin_amdgcn_mfma_i32_16x16x64_i8((a),(b),(c),0,0,0)

#define INV_D2 (1.0f / 4194304.0f)
#define INV_KV (1.0f / 1048576.0f)
#define INV_F  (1.0f / 16777216.0f)

__device__ __forceinline__ void glds16(const void* g, void* l) {
  __builtin_amdgcn_global_load_lds(
      (const __attribute__((address_space(1))) void*)g,
      (__attribute__((address_space(3))) void*)l, 16, 0, 0);
}

__device__ __forceinline__ float wred_sum(float v) {
#pragma unroll
  for (int o = 32; o; o >>= 1) v += __shfl_xor(v, o);
  return v;
}
__device__ __forceinline__ float wred_max(float v) {
#pragma unroll
  for (int o = 32; o; o >>= 1) v = fmaxf(v, __shfl_xor(v, o));
  return v;
}

__device__ __forceinline__ unsigned int packbf(float a, float b) {
  union { bf16 h[2]; unsigned int u; } x;
  x.h[0] = (bf16)a; x.h[1] = (bf16)b;
  return x.u;
}

// ---------------- dtype sniffer (inputs turned out fp32; keep robust) ----------------
__global__ void k_sniff(const unsigned short* __restrict__ x, int* __restrict__ flag) {
  int cnt = 0;
  for (int i = threadIdx.x; i < 2048; i += 64) {
    const unsigned short u = x[i];
    const int e = (u >> 7) & 0xFF;
    if (u == 0 || (e >= 100 && e <= 140)) cnt++;
  }
#pragma unroll
  for (int o = 32; o; o >>= 1) cnt += __shfl_xor(cnt, o);
  if (threadIdx.x == 0) flag[0] = (cnt >= 1844) ? 0 : 1;  // 0 = bf16, 1 = f32
}

// ---------------- small utility kernels ----------------

__global__ void k_zero(float* p, int n) {
  int i = threadIdx.x;
  if (i < n) p[i] = 0.0f;
}

// zero a float4-aligned buffer; grid = bytes/16/256
__global__ __launch_bounds__(256) void k_zerof(float4* __restrict__ p) {
  p[(size_t)blockIdx.x * 256 + threadIdx.x] = make_float4(0.f, 0.f, 0.f, 0.f);
}

// fused abs-sum over all 6 weights; segments in 64K-element units:
// wq 64 | wk 16 | wv 16 | wo 64 | w1 256 | w2 256  => grid = 672 blocks
__global__ __launch_bounds__(256) void k_abssum6(const void* __restrict__ p0, const void* __restrict__ p1,
                                                 const void* __restrict__ p2, const void* __restrict__ p3,
                                                 const void* __restrict__ p4, const void* __restrict__ p5,
                                                 const int* __restrict__ flag, float* __restrict__ out) {
  const int b = blockIdx.x, tid = threadIdx.x;
  const void* w; int seg, base;
  if (b < 64)       { w = p0; seg = 0; base = b; }
  else if (b < 80)  { w = p1; seg = 1; base = b - 64; }
  else if (b < 96)  { w = p2; seg = 2; base = b - 80; }
  else if (b < 160) { w = p3; seg = 3; base = b - 96; }
  else if (b < 416) { w = p4; seg = 4; base = b - 160; }
  else              { w = p5; seg = 5; base = b - 416; }
  const int f32 = flag[0];
  __shared__ float sred[4];
  float s = 0.0f;
  if (f32) {
    const float4* p = (const float4*)w + (size_t)base * 16384;
#pragma unroll 4
    for (int i = 0; i < 64; i++) {
      float4 a = p[i * 256 + tid];
      s += fabsf(a.x) + fabsf(a.y) + fabsf(a.z) + fabsf(a.w);
    }
  } else {
    const v8bf* p = (const v8bf*)w + (size_t)base * 8192;
#pragma unroll 4
    for (int i = 0; i < 32; i++) {
      v8bf v = p[i * 256 + tid];
#pragma unroll
      for (int j = 0; j < 8; j++) s += fabsf((float)v[j]);
    }
  }
  s = wred_sum(s);
  if ((tid & 63) == 0) sred[tid >> 6] = s;
  __syncthreads();
  if (tid == 0) atomicAdd(out + seg, sred[0] + sred[1] + sred[2] + sred[3]);
}

// fused ternary weight quant -> int8 for all 6 weights; 2048 elems/block:
// wq 2048 | wk 512 | wv 512 | wo 2048 | w1 8192 | w2 8192 => grid = 21504
__global__ __launch_bounds__(256) void k_wquant6(const void* __restrict__ p0, const void* __restrict__ p1,
                                                 const void* __restrict__ p2, const void* __restrict__ p3,
                                                 const void* __restrict__ p4, const void* __restrict__ p5,
                                                 i8* __restrict__ d0, i8* __restrict__ d1,
                                                 i8* __restrict__ d2, i8* __restrict__ d3,
                                                 i8* __restrict__ d4, i8* __restrict__ d5,
                                                 const float* __restrict__ wsum,
                                                 const int* __restrict__ flag) {
  const int b = blockIdx.x;
  const void* w; i8* o; int seg, base; float invn;
  if (b < 2048)       { w = p0; o = d0; seg = 0; base = b;         invn = INV_D2; }
  else if (b < 2560)  { w = p1; o = d1; seg = 1; base = b - 2048;  invn = INV_KV; }
  else if (b < 3072)  { w = p2; o = d2; seg = 2; base = b - 2560;  invn = INV_KV; }
  else if (b < 5120)  { w = p3; o = d3; seg = 3; base = b - 3072;  invn = INV_D2; }
  else if (b < 13312) { w = p4; o = d4; seg = 4; base = b - 5120;  invn = INV_F; }
  else                { w = p5; o = d5; seg = 5; base = b - 13312; invn = INV_F; }
  const int gid = base * 256 + threadIdx.x;
  const int i = gid * 8;
  const float ws = 1.0f / fmaxf(wsum[seg] * invn, 1e-5f);
  const int f32 = flag[0];
  float v[8];
  if (f32) {
    float4 a = ((const float4*)w)[gid * 2];
    float4 b4 = ((const float4*)w)[gid * 2 + 1];
    v[0] = a.x; v[1] = a.y; v[2] = a.z; v[3] = a.w;
    v[4] = b4.x; v[5] = b4.y; v[6] = b4.z; v[7] = b4.w;
  } else {
    v8bf t = *(const v8bf*)((const bf16*)w + i);
#pragma unroll
    for (int j = 0; j < 8; j++) v[j] = (float)t[j];
  }
  v8i8 r;
#pragma unroll
  for (int j = 0; j < 8; j++) {
    float t = rintf(v[j] * ws);
    r[j] = (i8)fminf(fmaxf(t, -1.0f), 1.0f);
  }
  *(v8i8*)(o + i) = r;
}

// LayerNorm + per-row absmax quantize -> int8.
template <bool XINT>
__global__ __launch_bounds__(256) void k_lnq(const void* __restrict__ x, const void* __restrict__ g,
                                             const void* __restrict__ b, i8* __restrict__ q,
                                             float* __restrict__ sc, const int* __restrict__ flag) {
  const int row = blockIdx.x, tid = threadIdx.x;
  const int f32 = flag[0];
  __shared__ float sred[4];
  float v[8];
#pragma unroll
  for (int i = 0; i < 8; i++) {
    const size_t idx = (size_t)row * 2048 + tid + 256 * i;
    if (XINT)      v[i] = ((const float*)x)[idx];
    else if (f32)  v[i] = ((const float*)x)[idx];
    else           v[i] = (float)((const bf16*)x)[idx];
  }
  float s = 0.0f;
#pragma unroll
  for (int i = 0; i < 8; i++) s += v[i];
  s = wred_sum(s);
  if ((tid & 63) == 0) sred[tid >> 6] = s;
  __syncthreads();
  const float mean = (sred[0] + sred[1] + sred[2] + sred[3]) * (1.0f / 2048.0f);
  __syncthreads();
  float vs = 0.0f;
#pragma unroll
  for (int i = 0; i < 8; i++) { float d = v[i] - mean; vs += d * d; }
  vs = wred_sum(vs);
  if ((tid & 63) == 0) sred[tid >> 6] = vs;
  __syncthreads();
  const float rstd = rsqrtf((sred[0] + sred[1] + sred[2] + sred[3]) * (1.0f / 2048.0f) + 1e-6f);
  __syncthreads();
  float hq[8];
  float am = 0.0f;
#pragma unroll
  for (int i = 0; i < 8; i++) {
    const int c = tid + 256 * i;
    const float gv = f32 ? ((const float*)g)[c] : (float)((const bf16*)g)[c];
    const float bv = f32 ? ((const float*)b)[c] : (float)((const bf16*)b)[c];
    hq[i] = (v[i] - mean) * rstd * gv + bv;
    am = fmaxf(am, fabsf(hq[i]));
  }
  am = wred_max(am);
  if ((tid & 63) == 0) sred[tid >> 6] = am;
  __syncthreads();
  am = fmaxf(fmaxf(sred[0], sred[1]), fmaxf(sred[2], sred[3]));
  const float cl = fmaxf(am, 1e-5f);
  const float s127 = 127.0f / cl;
#pragma unroll
  for (int i = 0; i < 8; i++) {
    float r = rintf(hq[i] * s127);
    r = fminf(fmaxf(r, -128.0f), 127.0f);
    q[(size_t)row * 2048 + tid + 256 * i] = (i8)r;
  }
  if (tid == 0) sc[row] = cl * (1.0f / 127.0f);
}

// plain per-row absmax quantize bf16 -> int8
template <int IT>
__global__ __launch_bounds__(256) void k_rowq(const bf16* __restrict__ in, i8* __restrict__ q,
                                              float* __restrict__ sc) {
  const int row = blockIdx.x, tid = threadIdx.x;
  const int C = IT * 256;
  __shared__ float sred[4];
  const bf16* xr = in + (size_t)row * C;
  float v[IT];
  float am = 0.0f;
#pragma unroll
  for (int i = 0; i < IT; i++) {
    v[i] = (float)xr[tid + 256 * i];
    am = fmaxf(am, fabsf(v[i]));
  }
  am = wred_max(am);
  if ((tid & 63) == 0) sred[tid >> 6] = am;
  __syncthreads();
  am = fmaxf(fmaxf(sred[0], sred[1]), fmaxf(sred[2], sred[3]));
  const float cl = fmaxf(am, 1e-5f);
  const float s127 = 127.0f / cl;
#pragma unroll
  for (int i = 0; i < IT; i++) {
    float r = rintf(v[i] * s127);
    r = fminf(fmaxf(r, -128.0f), 127.0f);
    q[(size_t)row * C + tid + 256 * i] = (i8)r;
  }
  if (tid == 0) sc[row] = cl * (1.0f / 127.0f);
}

// ---------------- int8 GEMM: double-buffered LDS, 1 barrier/K-step (T3-minimum) ----------------
// EPI 2: out bf16 = relu(sA[m]*cw*val)^2   (w1 -> F; direct, no split)
// EPI 4: atomicAdd i32 partial into out    (split-K; exact integer)
template <int EPI>
__global__ __launch_bounds__(256) void k_gemm(const i8* __restrict__ A, const i8* __restrict__ B,
                                              const float* __restrict__ sA,
                                              const float* __restrict__ wsum, float winv,
                                              void* __restrict__ out,
                                              int M, int N, int K, int Kc,
                                              const int* __restrict__ flag) {
  __shared__ __align__(16) i8 As[2][128 * 64];
  __shared__ __align__(16) i8 Bs[2][128 * 64];
  const int tid = threadIdx.x;
  const int lane = tid & 63;
  const int ml = lane & 15;
  const int q4 = lane >> 4;
  const int wid = tid >> 6;
  const int wM = wid >> 1;
  const int wN = wid & 1;
  const int m0 = blockIdx.y * 128;
  const int n0 = blockIdx.x * 128;

  const int r0 = tid >> 2;           // 0..63
  const int c0 = (tid & 3) * 16;     // 0,16,32,48
  const i8* Ag0 = A + (size_t)(m0 + r0) * K + c0;
  const i8* Ag1 = Ag0 + (size_t)64 * K;
  const i8* Bg0 = B + (size_t)(n0 + r0) * K + c0;
  const i8* Bg1 = Bg0 + (size_t)64 * K;
  const int l0 = wid * 1024;         // lane l of wave w -> wavebase + l*16B
  const int l1 = 4096 + wid * 1024;

  v4i acc[4][4] = {};

  const int kbeg = blockIdx.z * Kc;
  const int kfin = kbeg + Kc;
  glds16(Ag0 + kbeg, &As[0][l0]);
  glds16(Ag1 + kbeg, &As[0][l1]);
  glds16(Bg0 + kbeg, &Bs[0][l0]);
  glds16(Bg1 + kbeg, &Bs[0][l1]);
  __syncthreads();
  int cb = 0;
  for (int k0 = kbeg; k0 < kfin; k0 += 64) {
    const int kn = k0 + 64;
    if (kn < kfin) {  // issue next-tile staging before compute (hides latency)
      glds16(Ag0 + kn, &As[cb ^ 1][l0]);
      glds16(Ag1 + kn, &As[cb ^ 1][l1]);
      glds16(Bg0 + kn, &Bs[cb ^ 1][l0]);
      glds16(Bg1 + kn, &Bs[cb ^ 1][l1]);
    }
    v4i af[4], bfr[4];
#pragma unroll
    for (int i = 0; i < 4; i++) af[i] = *(const v4i*)&As[cb][(wM * 64 + i * 16 + ml) * 64 + q4 * 16];
#pragma unroll
    for (int j = 0; j < 4; j++) bfr[j] = *(const v4i*)&Bs[cb][(wN * 64 + j * 16 + ml) * 64 + q4 * 16];
#pragma unroll
    for (int i = 0; i < 4; i++)
#pragma unroll
      for (int j = 0; j < 4; j++) acc[i][j] = MFMA_I8(af[i], bfr[j], acc[i][j]);
    __syncthreads();  // drains this wave's vmem (staging) + all waves' reads
    cb ^= 1;
  }

  if (EPI == 4) {
    int* ob = (int*)out;
#pragma unroll
    for (int i = 0; i < 4; i++)
#pragma unroll
      for (int r = 0; r < 4; r++) {
        const int row = m0 + wM * 64 + i * 16 + q4 * 4 + r;
#pragma unroll
        for (int j = 0; j < 4; j++) {
          const int col = n0 + wN * 64 + j * 16 + ml;
          atomicAdd(ob + (size_t)row * N + col, acc[i][j][r]);
        }
      }
    return;
  }

  // EPI == 2 (direct relu^2 bf16)
  const float cw = fmaxf(wsum[0] * winv, 1e-5f);
#pragma unroll
  for (int i = 0; i < 4; i++) {
#pragma unroll
    for (int r = 0; r < 4; r++) {
      const int row = m0 + wM * 64 + i * 16 + q4 * 4 + r;
      const float sa = sA[row] * cw;
#pragma unroll
      for (int j = 0; j < 4; j++) {
        const int col = n0 + wN * 64 + j * 16 + ml;
        const float val = (float)acc[i][j][r] * sa;
        float u = fmaxf(val, 0.0f);
        ((bf16*)out)[(size_t)row * N + col] = (bf16)(u * u);
      }
    }
  }
}

// ---------------- split-K scale/residual epilogues (i32 acc in) ----------------
// MODE 1: out f32  = resid(flag-typed) + acc*sA[row]*cw (x1)
// MODE 2: out flag-typed = x1(f32) + acc*sA[row]*cw     (final)
// MODE 3: out bf16 = acc*sA[col]*cw                     (Vt: row=d, col-scale s1[t])
template <int MODE>
__global__ __launch_bounds__(256) void k_epi(const int* __restrict__ acc, int lda, int cofs,
                                             int ncols,
                                             const float* __restrict__ sA,
                                             const float* __restrict__ wsum, float winv,
                                             const void* __restrict__ resid,
                                             void* __restrict__ out,
                                             const int* __restrict__ flag) {
  const int row = blockIdx.x, tid = threadIdx.x;
  const float cw = fmaxf(wsum[0] * winv, 1e-5f);
  const float srow = (MODE == 3) ? cw : sA[row] * cw;
  const int f32 = flag[0];
  for (int c = tid * 4; c < ncols; c += 1024) {
    const v4i a = *(const v4i*)(acc + (size_t)row * lda + cofs + c);
    float s0 = srow, s1 = srow, s2 = srow, s3 = srow;
    if (MODE == 3) {
      float4 sc = *(const float4*)(sA + c);
      s0 *= sc.x; s1 *= sc.y; s2 *= sc.z; s3 *= sc.w;
    }
    const float v0 = (float)a[0] * s0, v1 = (float)a[1] * s1;
    const float v2 = (float)a[2] * s2, v3 = (float)a[3] * s3;
    const size_t o = (size_t)row * ncols + c;
    if (MODE == 3) {
      v4bf r;
      r[0] = (bf16)v0; r[1] = (bf16)v1; r[2] = (bf16)v2; r[3] = (bf16)v3;
      *(v4bf*)((bf16*)out + o) = r;
    } else if (MODE == 1) {
      float4 rv;
      if (f32) {
        rv = *(const float4*)((const float*)resid + o);
      } else {
        const v4bf rb = *(const v4bf*)((const bf16*)resid + o);
        rv = make_float4((float)rb[0], (float)rb[1], (float)rb[2], (float)rb[3]);
      }
      *(float4*)((float*)out + o) = make_float4(rv.x + v0, rv.y + v1, rv.z + v2, rv.w + v3);
    } else {  // MODE 2
      const float4 rv = *(const float4*)((const float*)resid + o);
      const float o0 = rv.x + v0, o1 = rv.y + v1, o2 = rv.z + v2, o3 = rv.w + v3;
      if (f32) {
        *(float4*)((float*)out + o) = make_float4(o0, o1, o2, o3);
      } else {
        v4bf r;
        r[0] = (bf16)o0; r[1] = (bf16)o1; r[2] = (bf16)o2; r[3] = (bf16)o3;
        *(v4bf*)((bf16*)out + o) = r;
      }
    }
  }
}

// fused Q+K epilogue: one pass over accQK rows [2560]: cols 0-2047 -> Qb, 2048-2559 -> Kbuf
__global__ __launch_bounds__(256) void k_epiQK(const int* __restrict__ acc,
                                               const float* __restrict__ sA,
                                               const float* __restrict__ wsum,
                                               bf16* __restrict__ Qb, bf16* __restrict__ Kbuf) {
  const int row = blockIdx.x, tid = threadIdx.x;
  const float cw0 = fmaxf(wsum[0] * INV_D2, 1e-5f);
  const float cw1 = fmaxf(wsum[1] * INV_KV, 1e-5f);
  const float sa = sA[row];
  for (int c = tid * 4; c < 2560; c += 1024) {
    const v4i a = *(const v4i*)(acc + (size_t)row * 2560 + c);
    const float s = sa * (c < 2048 ? cw0 : cw1);
    v4bf r;
#pragma unroll
    for (int j = 0; j < 4; j++) r[j] = (bf16)((float)a[j] * s);
    if (c < 2048) *(v4bf*)(Qb + (size_t)row * 2048 + c) = r;
    else          *(v4bf*)(Kbuf + (size_t)row * 512 + (c - 2048)) = r;
  }
}

// ---------------- MFMA flash attention (causal, GQA 32q/8kv heads, D=64) ----------------
// Swapped-operand 32x32, softmax in-register, no LDS/barriers; grid (64,32).
// KVBLK=64 ILP2: two independent 32-row K blocks per iteration -> two QK chains,
// 8 PV MFMAs, 16 loads all independent (hides MFMA+mem latency at 2 waves/SIMD);
// loop-carried softmax serial points (rescale, reduce, l/m update) paid half as often.
// Causal mask only on diagonal-crossing block; fully-masked half contributes 0 and
// V reads stay in-bounds (max kb=1984 -> rows <=2047).
__global__ __launch_bounds__(64) void k_attn(const bf16* __restrict__ Q, const bf16* __restrict__ Kb,
                                             const bf16* __restrict__ Vt, bf16* __restrict__ O) {
  const int h = blockIdx.y;
  const int kvh = h >> 2;
  const int t = (blockIdx.x + ((h >> 2) << 3)) & 63;  // balanced q-tile swizzle
  const int qw0 = t * 32;
  const int lane = threadIdx.x;
  const int ql = lane & 31;
  const int hi = lane >> 5;

  v8bf qf[4];
  {
    const bf16* qp = Q + (size_t)(qw0 + ql) * 2048 + h * 64 + hi * 8;
#pragma unroll
    for (int c = 0; c < 4; c++) qf[c] = *(const v8bf*)(qp + c * 16);
  }

  float m = -1e30f, l = 0.0f;
  f32x16 acc0 = {}, acc1 = {};

  const bf16* kbase = Kb + kvh * 64 + hi * 8;
  const bf16* vbase = Vt + (size_t)(kvh * 64 + ql) * 2048 + hi * 8;

  for (int kb = 0; kb < qw0 + 32; kb += 64) {
    // two independent S^T chains over d (4 chunks of 16)
    f32x16 s0 = {}, s1 = {};
    {
      const bf16* kp = kbase + (size_t)(kb + ql) * 512;
      const bf16* kp2 = kp + 32 * 512;
#pragma unroll
      for (int c = 0; c < 4; c++) {
        const v8bf ka = *(const v8bf*)(kp + c * 16);
        const v8bf kc = *(const v8bf*)(kp2 + c * 16);
        s0 = MFMA32(ka, qf[c], s0);
        s1 = MFMA32(kc, qf[c], s1);
      }
    }
    const bool needmask = (kb + 64 > qw0);
    float p0[16], p1[16];
    float rm = -1e30f;
#pragma unroll
    for (int r = 0; r < 16; r++) {
      float v0 = s0[r] * 0.125f;
      float v1 = s1[r] * 0.125f;
      if (needmask) {
        const int k0 = kb + (r & 3) + ((r >> 2) << 3) + (hi << 2);
        const int qg = qw0 + ql;
        if (k0 > qg) v0 = -1e30f;
        if (k0 + 32 > qg) v1 = -1e30f;
      }
      p0[r] = v0; p1[r] = v1;
      rm = fmaxf(rm, fmaxf(v0, v1));
    }
    rm = fmaxf(rm, __shfl_xor(rm, 32));
    const float mn = fmaxf(m, rm);
    const float alpha = __expf(m - mn);
    m = mn;
    float rs = 0.0f;
#pragma unroll
    for (int r = 0; r < 16; r++) {
      p0[r] = __expf(p0[r] - mn);
      p1[r] = __expf(p1[r] - mn);
      rs += p0[r] + p1[r];
    }
    rs += __shfl_xor(rs, 32);
    l = l * alpha + rs;
#pragma unroll
    for (int r = 0; r < 16; r++) { acc0[r] *= alpha; acc1[r] *= alpha; }

    // pack P^T -> PV B-frags: p0 -> B0(k0..15),B1(k16..31); p1 -> B2,B3 (k32..63)
    unsigned int w0 = packbf(p0[0], p0[1]),   w2 = packbf(p0[4], p0[5]);
    unsigned int w1 = packbf(p0[2], p0[3]),   w3 = packbf(p0[6], p0[7]);
    unsigned int x0 = packbf(p0[8], p0[9]),   x2 = packbf(p0[12], p0[13]);
    unsigned int x1 = packbf(p0[10], p0[11]), x3 = packbf(p0[14], p0[15]);
    unsigned int y0 = packbf(p1[0], p1[1]),   y2 = packbf(p1[4], p1[5]);
    unsigned int y1 = packbf(p1[2], p1[3]),   y3 = packbf(p1[6], p1[7]);
    unsigned int z0 = packbf(p1[8], p1[9]),   z2 = packbf(p1[12], p1[13]);
    unsigned int z1 = packbf(p1[10], p1[11]), z3 = packbf(p1[14], p1[15]);
    asm("v_permlane32_swap_b32 %0, %1" : "+v"(w0), "+v"(w2));
    asm("v_permlane32_swap_b32 %0, %1" : "+v"(w1), "+v"(w3));
    asm("v_permlane32_swap_b32 %0, %1" : "+v"(x0), "+v"(x2));
    asm("v_permlane32_swap_b32 %0, %1" : "+v"(x1), "+v"(x3));
    asm("v_permlane32_swap_b32 %0, %1" : "+v"(y0), "+v"(y2));
    asm("v_permlane32_swap_b32 %0, %1" : "+v"(y1), "+v"(y3));
    asm("v_permlane32_swap_b32 %0, %1" : "+v"(z0), "+v"(z2));
    asm("v_permlane32_swap_b32 %0, %1" : "+v"(z1), "+v"(z3));
    union BU { unsigned int u[4]; v8bf v; } B0, B1, B2, B3;
    B0.u[0] = w0; B0.u[1] = w1; B0.u[2] = w2; B0.u[3] = w3;
    B1.u[0] = x0; B1.u[1] = x1; B1.u[2] = x2; B1.u[3] = x3;
    B2.u[0] = y0; B2.u[1] = y1; B2.u[2] = y2; B2.u[3] = y3;
    B3.u[0] = z0; B3.u[1] = z1; B3.u[2] = z2; B3.u[3] = z3;

    // O^T += V^T . P^T over k=0..63 (4 chunks), both d-halves
    const bf16* vp = vbase + kb;
    const v8bf v00 = *(const v8bf*)(vp);
    const v8bf v01 = *(const v8bf*)(vp + 16);
    const v8bf v02 = *(const v8bf*)(vp + 32);
    const v8bf v03 = *(const v8bf*)(vp + 48);
    acc0 = MFMA32(v00, B0.v, acc0);
    acc0 = MFMA32(v01, B1.v, acc0);
    acc0 = MFMA32(v02, B2.v, acc0);
    acc0 = MFMA32(v03, B3.v, acc0);
    const bf16* vq = vp + (size_t)32 * 2048;
    const v8bf v10 = *(const v8bf*)(vq);
    const v8bf v11 = *(const v8bf*)(vq + 16);
    const v8bf v12 = *(const v8bf*)(vq + 32);
    const v8bf v13 = *(const v8bf*)(vq + 48);
    acc1 = MFMA32(v10, B0.v, acc1);
    acc1 = MFMA32(v11, B1.v, acc1);
    acc1 = MFMA32(v12, B2.v, acc1);
    acc1 = MFMA32(v13, B3.v, acc1);
  }

  const float inv = 1.0f / l;
  unsigned int* op = (unsigned int*)(O + (size_t)(qw0 + ql) * 2048 + h * 64);
#pragma unroll
  for (int r = 0; r < 16; r += 2) {
    const int d = (r & 3) + ((r >> 2) << 3) + (hi << 2);
    op[d >> 1] = packbf(acc0[r] * inv, acc0[r + 1] * inv);
    op[(d >> 1) + 16] = packbf(acc1[r] * inv, acc1[r + 1] * inv);
  }
}

// ---------------- launcher ----------------
// Workspace (96 MB + 64 KB), offsets from `big` (MB):
//   0-16   w1z(i8) [->FFN gemm]  ... then fq(i8) after rowq32
//   16-32  w2z(i8)
//   32-36  wqz  36-37 wkz (contiguous [2560][2048])  37-38 wvz  38-42 woz
//   42-46  xq1(i8) [->proj gemms]   ... then oq(i8) after rowq8
//   46-66  accQK(i32) [->epiQK]     ... then accO(i32) [wo gemm->epi1]
//   66-70  accVt(i32) [->epi3]
//   70-72  Kbuf  72-74 Vt  74-82 Qb [epis->attn]
//   82-90  Ob                       [attn->rowq8]
//   80-96  x1(f32)                  [epi1->end; Qb/Ob dead by then]
//   74-78  xq2(i8)  42-74 Fb(bf16)  [lnq2->gemm2->rowq32]
//   42-58  accF(i32)                [w2 gemm->epi2]
extern "C" void kernel_launch(void* const* d_in, const int* in_sizes, int n_in, void* d_out,
                              int out_size, void* d_ws, size_t ws_size, hipStream_t stream) {
  const void* x = d_in[0];
  const void* g1 = d_in[1];
  const void* b1 = d_in[2];
  const void* g2 = d_in[3];
  const void* b2 = d_in[4];
  const void* wq = d_in[5];
  const void* wk = d_in[6];
  const void* wv = d_in[7];
  const void* wo = d_in[8];
  const void* w1 = d_in[9];
  const void* w2 = d_in[10];

  char* ws = (char*)d_ws;
  const size_t MB = 1ull << 20;
  float* wsum = (float*)ws;
  float* s1 = (float*)(ws + 8192);
  float* so = (float*)(ws + 16384);
  float* s2 = (float*)(ws + 24576);
  float* sf = (float*)(ws + 32768);
  int* flag = (int*)(ws + 40960);
  char* big = ws + 65536;

  i8* w1z = (i8*)(big);
  i8* fq  = (i8*)(big);
  i8* w2z = (i8*)(big + 16 * MB);
  i8* wqz = (i8*)(big + 32 * MB);   // [2560][2048] contiguous with wkz
  i8* wkz = (i8*)(big + 36 * MB);
  i8* wvz = (i8*)(big + 37 * MB);
  i8* woz = (i8*)(big + 38 * MB);
  i8* xq1 = (i8*)(big + 42 * MB);
  i8* oq  = xq1;
  int* accQK = (int*)(big + 46 * MB);   // [2048][2560]
  int* accVt = (int*)(big + 66 * MB);   // [512][2048]
  bf16* Kbuf = (bf16*)(big + 70 * MB);
  bf16* Vt   = (bf16*)(big + 72 * MB);
  bf16* Qb   = (bf16*)(big + 74 * MB);
  bf16* Ob   = (bf16*)(big + 82 * MB);
  int* accO  = (int*)(big + 46 * MB);   // [2048][2048]
  float* x1  = (float*)(big + 80 * MB);
  i8* xq2 = (i8*)(big + 74 * MB);
  bf16* Fb   = (bf16*)(big + 42 * MB);  // [2048][8192]
  int* accF  = (int*)(big + 42 * MB);   // [2048][2048]

  k_sniff<<<1, 64, 0, stream>>>((const unsigned short*)x, flag);
  k_zero<<<1, 64, 0, stream>>>(wsum, 8);
  // zero accQK+accVt (contiguous 24MB @46-70)
  k_zerof<<<6144, 256, 0, stream>>>((float4*)accQK);

  k_abssum6<<<672, 256, 0, stream>>>(wq, wk, wv, wo, w1, w2, flag, wsum);
  k_wquant6<<<21504, 256, 0, stream>>>(wq, wk, wv, wo, w1, w2,
                                       wqz, wkz, wvz, woz, w1z, w2z, wsum, flag);

  // ---- attention sublayer ----
  k_lnq<false><<<2048, 256, 0, stream>>>(x, g1, b1, xq1, s1, flag);
  // fused Q+K projection: B = [wqz;wkz] (2560 rows), split-K x4 -> accQK
  k_gemm<4><<<dim3(20, 16, 4), 256, 0, stream>>>(xq1, wqz, s1, wsum + 0, INV_D2, accQK,
                                                 2048, 2560, 2048, 512, flag);
  // V^T directly: C[d][t] = wvz[d].xq1[t], split-K x4 -> accVt
  k_gemm<4><<<dim3(16, 4, 4), 256, 0, stream>>>(wvz, xq1, s1, wsum + 2, INV_KV, accVt,
                                                512, 2048, 2048, 512, flag);
  k_epiQK<<<2048, 256, 0, stream>>>(accQK, s1, wsum, Qb, Kbuf);
  k_epi<3><<<512, 256, 0, stream>>>(accVt, 2048, 0, 2048, s1, wsum + 2, INV_KV, nullptr, Vt, flag);
  k_attn<<<dim3(64, 32), 64, 0, stream>>>(Qb, Kbuf, Vt, Ob);
  k_rowq<8><<<2048, 256, 0, stream>>>(Ob, oq, so);
  k_zerof<<<4096, 256, 0, stream>>>((float4*)accO);  // after epiQK read accQK
  k_gemm<4><<<dim3(16, 16, 4), 256, 0, stream>>>(oq, woz, so, wsum + 3, INV_D2, accO,
                                                 2048, 2048, 2048, 512, flag);
  k_epi<1><<<2048, 256, 0, stream>>>(accO, 2048, 0, 2048, so, wsum + 3, INV_D2, x, x1, flag);

  // ---- FFN sublayer ----
  k_lnq<true><<<2048, 256, 0, stream>>>(x1, g2, b2, xq2, s2, flag);
  k_gemm<2><<<dim3(64, 16, 1), 256, 0, stream>>>(xq2, w1z, s2, wsum + 4, INV_F, Fb,
                                                 2048, 8192, 2048, 2048, flag);
  k_rowq<32><<<2048, 256, 0, stream>>>(Fb, fq, sf);  // fq overwrites dead w1z
  k_zerof<<<4096, 256, 0, stream>>>((float4*)accF);  // after rowq read Fb
  k_gemm<4><<<dim3(16, 16, 4), 256, 0, stream>>>(fq, w2z, sf, wsum + 5, INV_F, accF,
                                                 2048, 2048, 8192, 2048, flag);
  k_epi<2><<<2048, 256, 0, stream>>>(accF, 2048, 0, 2048, sf, wsum + 5, INV_F, x1, d_out, flag);
}

// Round 8
// 657.080 us; speedup vs baseline: 1.1470x; 1.0047x over previous
//
#include <hip/hip_runtime.h>
#include <hip/hip_bf16.h>
#include <stdint.h>

typedef __bf16 bf16;
typedef signed char i8;
typedef __bf16 v8bf __attribute__((ext_vector_type(8)));
typedef __bf16 v4bf __attribute__((ext_vector_type(4)));
typedef signed char v8i8 __attribute__((ext_vector_type(8)));
typedef int    v4i  __attribute__((ext_vector_type(4)));
typedef float  f32x16 __attribute__((ext_vector_type(16)));

#define MFMA32(a,b,c)   __builtin_amdgcn_mfma_f32_32x32x16_bf16((a),(b),(c),0,0,0)
#define MFMA_I8(a,b,c)  __builtin_amdgcn_mfma_i32_16x16x64_i8((a),(b),(c),0,0,0)

#define INV_D2 (1.0f / 4194304.0f)
#define INV_KV (1.0f / 1048576.0f)
#define INV_F  (1.0f / 16777216.0f)

__device__ __forceinline__ void glds16(const void* g, void* l) {
  __builtin_amdgcn_global_load_lds(
      (const __attribute__((address_space(1))) void*)g,
      (__attribute__((address_space(3))) void*)l, 16, 0, 0);
}

__device__ __forceinline__ float wred_sum(float v) {
#pragma unroll
  for (int o = 32; o; o >>= 1) v += __shfl_xor(v, o);
  return v;
}
__device__ __forceinline__ float wred_max(float v) {
#pragma unroll
  for (int o = 32; o; o >>= 1) v = fmaxf(v, __shfl_xor(v, o));
  return v;
}

__device__ __forceinline__ unsigned int packbf(float a, float b) {
  union { bf16 h[2]; unsigned int u; } x;
  x.h[0] = (bf16)a; x.h[1] = (bf16)b;
  return x.u;
}

// ---------------- dtype sniffer (inputs turned out fp32; keep robust) ----------------
__global__ void k_sniff(const unsigned short* __restrict__ x, int* __restrict__ flag) {
  int cnt = 0;
  for (int i = threadIdx.x; i < 2048; i += 64) {
    const unsigned short u = x[i];
    const int e = (u >> 7) & 0xFF;
    if (u == 0 || (e >= 100 && e <= 140)) cnt++;
  }
#pragma unroll
  for (int o = 32; o; o >>= 1) cnt += __shfl_xor(cnt, o);
  if (threadIdx.x == 0) flag[0] = (cnt >= 1844) ? 0 : 1;  // 0 = bf16, 1 = f32
}

// ---------------- small utility kernels ----------------

__global__ void k_zero(float* p, int n) {
  int i = threadIdx.x;
  if (i < n) p[i] = 0.0f;
}

// zero a float4-aligned buffer; grid = bytes/16/256
__global__ __launch_bounds__(256) void k_zerof(float4* __restrict__ p) {
  p[(size_t)blockIdx.x * 256 + threadIdx.x] = make_float4(0.f, 0.f, 0.f, 0.f);
}

// fused abs-sum over all 6 weights; segments in 64K-element units:
// wq 64 | wk 16 | wv 16 | wo 64 | w1 256 | w2 256  => grid = 672 blocks
__global__ __launch_bounds__(256) void k_abssum6(const void* __restrict__ p0, const void* __restrict__ p1,
                                                 const void* __restrict__ p2, const void* __restrict__ p3,
                                                 const void* __restrict__ p4, const void* __restrict__ p5,
                                                 const int* __restrict__ flag, float* __restrict__ out) {
  const int b = blockIdx.x, tid = threadIdx.x;
  const void* w; int seg, base;
  if (b < 64)       { w = p0; seg = 0; base = b; }
  else if (b < 80)  { w = p1; seg = 1; base = b - 64; }
  else if (b < 96)  { w = p2; seg = 2; base = b - 80; }
  else if (b < 160) { w = p3; seg = 3; base = b - 96; }
  else if (b < 416) { w = p4; seg = 4; base = b - 160; }
  else              { w = p5; seg = 5; base = b - 416; }
  const int f32 = flag[0];
  __shared__ float sred[4];
  float s = 0.0f;
  if (f32) {
    const float4* p = (const float4*)w + (size_t)base * 16384;
#pragma unroll 4
    for (int i = 0; i < 64; i++) {
      float4 a = p[i * 256 + tid];
      s += fabsf(a.x) + fabsf(a.y) + fabsf(a.z) + fabsf(a.w);
    }
  } else {
    const v8bf* p = (const v8bf*)w + (size_t)base * 8192;
#pragma unroll 4
    for (int i = 0; i < 32; i++) {
      v8bf v = p[i * 256 + tid];
#pragma unroll
      for (int j = 0; j < 8; j++) s += fabsf((float)v[j]);
    }
  }
  s = wred_sum(s);
  if ((tid & 63) == 0) sred[tid >> 6] = s;
  __syncthreads();
  if (tid == 0) atomicAdd(out + seg, sred[0] + sred[1] + sred[2] + sred[3]);
}

// fused ternary weight quant -> int8 for all 6 weights; 2048 elems/block:
// wq 2048 | wk 512 | wv 512 | wo 2048 | w1 8192 | w2 8192 => grid = 21504
__global__ __launch_bounds__(256) void k_wquant6(const void* __restrict__ p0, const void* __restrict__ p1,
                                                 const void* __restrict__ p2, const void* __restrict__ p3,
                                                 const void* __restrict__ p4, const void* __restrict__ p5,
                                                 i8* __restrict__ d0, i8* __restrict__ d1,
                                                 i8* __restrict__ d2, i8* __restrict__ d3,
                                                 i8* __restrict__ d4, i8* __restrict__ d5,
                                                 const float* __restrict__ wsum,
                                                 const int* __restrict__ flag) {
  const int b = blockIdx.x;
  const void* w; i8* o; int seg, base; float invn;
  if (b < 2048)       { w = p0; o = d0; seg = 0; base = b;         invn = INV_D2; }
  else if (b < 2560)  { w = p1; o = d1; seg = 1; base = b - 2048;  invn = INV_KV; }
  else if (b < 3072)  { w = p2; o = d2; seg = 2; base = b - 2560;  invn = INV_KV; }
  else if (b < 5120)  { w = p3; o = d3; seg = 3; base = b - 3072;  invn = INV_D2; }
  else if (b < 13312) { w = p4; o = d4; seg = 4; base = b - 5120;  invn = INV_F; }
  else                { w = p5; o = d5; seg = 5; base = b - 13312; invn = INV_F; }
  const int gid = base * 256 + threadIdx.x;
  const int i = gid * 8;
  const float ws = 1.0f / fmaxf(wsum[seg] * invn, 1e-5f);
  const int f32 = flag[0];
  float v[8];
  if (f32) {
    float4 a = ((const float4*)w)[gid * 2];
    float4 b4 = ((const float4*)w)[gid * 2 + 1];
    v[0] = a.x; v[1] = a.y; v[2] = a.z; v[3] = a.w;
    v[4] = b4.x; v[5] = b4.y; v[6] = b4.z; v[7] = b4.w;
  } else {
    v8bf t = *(const v8bf*)((const bf16*)w + i);
#pragma unroll
    for (int j = 0; j < 8; j++) v[j] = (float)t[j];
  }
  v8i8 r;
#pragma unroll
  for (int j = 0; j < 8; j++) {
    float t = rintf(v[j] * ws);
    r[j] = (i8)fminf(fmaxf(t, -1.0f), 1.0f);
  }
  *(v8i8*)(o + i) = r;
}

// LayerNorm + per-row absmax quantize -> int8.
template <bool XINT>
__global__ __launch_bounds__(256) void k_lnq(const void* __restrict__ x, const void* __restrict__ g,
                                             const void* __restrict__ b, i8* __restrict__ q,
                                             float* __restrict__ sc, const int* __restrict__ flag) {
  const int row = blockIdx.x, tid = threadIdx.x;
  const int f32 = flag[0];
  __shared__ float sred[4];
  float v[8];
#pragma unroll
  for (int i = 0; i < 8; i++) {
    const size_t idx = (size_t)row * 2048 + tid + 256 * i;
    if (XINT)      v[i] = ((const float*)x)[idx];
    else if (f32)  v[i] = ((const float*)x)[idx];
    else           v[i] = (float)((const bf16*)x)[idx];
  }
  float s = 0.0f;
#pragma unroll
  for (int i = 0; i < 8; i++) s += v[i];
  s = wred_sum(s);
  if ((tid & 63) == 0) sred[tid >> 6] = s;
  __syncthreads();
  const float mean = (sred[0] + sred[1] + sred[2] + sred[3]) * (1.0f / 2048.0f);
  __syncthreads();
  float vs = 0.0f;
#pragma unroll
  for (int i = 0; i < 8; i++) { float d = v[i] - mean; vs += d * d; }
  vs = wred_sum(vs);
  if ((tid & 63) == 0) sred[tid >> 6] = vs;
  __syncthreads();
  const float rstd = rsqrtf((sred[0] + sred[1] + sred[2] + sred[3]) * (1.0f / 2048.0f) + 1e-6f);
  __syncthreads();
  float hq[8];
  float am = 0.0f;
#pragma unroll
  for (int i = 0; i < 8; i++) {
    const int c = tid + 256 * i;
    const float gv = f32 ? ((const float*)g)[c] : (float)((const bf16*)g)[c];
    const float bv = f32 ? ((const float*)b)[c] : (float)((const bf16*)b)[c];
    hq[i] = (v[i] - mean) * rstd * gv + bv;
    am = fmaxf(am, fabsf(hq[i]));
  }
  am = wred_max(am);
  if ((tid & 63) == 0) sred[tid >> 6] = am;
  __syncthreads();
  am = fmaxf(fmaxf(sred[0], sred[1]), fmaxf(sred[2], sred[3]));
  const float cl = fmaxf(am, 1e-5f);
  const float s127 = 127.0f / cl;
#pragma unroll
  for (int i = 0; i < 8; i++) {
    float r = rintf(hq[i] * s127);
    r = fminf(fmaxf(r, -128.0f), 127.0f);
    q[(size_t)row * 2048 + tid + 256 * i] = (i8)r;
  }
  if (tid == 0) sc[row] = cl * (1.0f / 127.0f);
}

// plain per-row absmax quantize bf16 -> int8
template <int IT>
__global__ __launch_bounds__(256) void k_rowq(const bf16* __restrict__ in, i8* __restrict__ q,
                                              float* __restrict__ sc) {
  const int row = blockIdx.x, tid = threadIdx.x;
  const int C = IT * 256;
  __shared__ float sred[4];
  const bf16* xr = in + (size_t)row * C;
  float v[IT];
  float am = 0.0f;
#pragma unroll
  for (int i = 0; i < IT; i++) {
    v[i] = (float)xr[tid + 256 * i];
    am = fmaxf(am, fabsf(v[i]));
  }
  am = wred_max(am);
  if ((tid & 63) == 0) sred[tid >> 6] = am;
  __syncthreads();
  am = fmaxf(fmaxf(sred[0], sred[1]), fmaxf(sred[2], sred[3]));
  const float cl = fmaxf(am, 1e-5f);
  const float s127 = 127.0f / cl;
#pragma unroll
  for (int i = 0; i < IT; i++) {
    float r = rintf(v[i] * s127);
    r = fminf(fmaxf(r, -128.0f), 127.0f);
    q[(size_t)row * C + tid + 256 * i] = (i8)r;
  }
  if (tid == 0) sc[row] = cl * (1.0f / 127.0f);
}

// ---------------- int8 GEMM: double-buffered LDS, 1 barrier/K-step ----------------
// EPI 2: out bf16 = relu(sA[m]*cw*val)^2   (w1 -> F; direct, no split)
// EPI 4: atomicAdd i32 partial into out    (split-K; exact integer)
template <int EPI>
__global__ __launch_bounds__(256) void k_gemm(const i8* __restrict__ A, const i8* __restrict__ B,
                                              const float* __restrict__ sA,
                                              const float* __restrict__ wsum, float winv,
                                              void* __restrict__ out,
                                              int M, int N, int K, int Kc,
                                              const int* __restrict__ flag) {
  __shared__ __align__(16) i8 As[2][128 * 64];
  __shared__ __align__(16) i8 Bs[2][128 * 64];
  const int tid = threadIdx.x;
  const int lane = tid & 63;
  const int ml = lane & 15;
  const int q4 = lane >> 4;
  const int wid = tid >> 6;
  const int wM = wid >> 1;
  const int wN = wid & 1;
  const int m0 = blockIdx.y * 128;
  const int n0 = blockIdx.x * 128;

  const int r0 = tid >> 2;           // 0..63
  const int c0 = (tid & 3) * 16;     // 0,16,32,48
  const i8* Ag0 = A + (size_t)(m0 + r0) * K + c0;
  const i8* Ag1 = Ag0 + (size_t)64 * K;
  const i8* Bg0 = B + (size_t)(n0 + r0) * K + c0;
  const i8* Bg1 = Bg0 + (size_t)64 * K;
  const int l0 = wid * 1024;         // lane l of wave w -> wavebase + l*16B
  const int l1 = 4096 + wid * 1024;

  v4i acc[4][4] = {};

  const int kbeg = blockIdx.z * Kc;
  const int kfin = kbeg + Kc;
  glds16(Ag0 + kbeg, &As[0][l0]);
  glds16(Ag1 + kbeg, &As[0][l1]);
  glds16(Bg0 + kbeg, &Bs[0][l0]);
  glds16(Bg1 + kbeg, &Bs[0][l1]);
  __syncthreads();
  int cb = 0;
  for (int k0 = kbeg; k0 < kfin; k0 += 64) {
    const int kn = k0 + 64;
    if (kn < kfin) {  // issue next-tile staging before compute (hides latency)
      glds16(Ag0 + kn, &As[cb ^ 1][l0]);
      glds16(Ag1 + kn, &As[cb ^ 1][l1]);
      glds16(Bg0 + kn, &Bs[cb ^ 1][l0]);
      glds16(Bg1 + kn, &Bs[cb ^ 1][l1]);
    }
    v4i af[4], bfr[4];
#pragma unroll
    for (int i = 0; i < 4; i++) af[i] = *(const v4i*)&As[cb][(wM * 64 + i * 16 + ml) * 64 + q4 * 16];
#pragma unroll
    for (int j = 0; j < 4; j++) bfr[j] = *(const v4i*)&Bs[cb][(wN * 64 + j * 16 + ml) * 64 + q4 * 16];
#pragma unroll
    for (int i = 0; i < 4; i++)
#pragma unroll
      for (int j = 0; j < 4; j++) acc[i][j] = MFMA_I8(af[i], bfr[j], acc[i][j]);
    __syncthreads();  // drains this wave's vmem (staging) + all waves' reads
    cb ^= 1;
  }

  if (EPI == 4) {
    int* ob = (int*)out;
#pragma unroll
    for (int i = 0; i < 4; i++)
#pragma unroll
      for (int r = 0; r < 4; r++) {
        const int row = m0 + wM * 64 + i * 16 + q4 * 4 + r;
#pragma unroll
        for (int j = 0; j < 4; j++) {
          const int col = n0 + wN * 64 + j * 16 + ml;
          atomicAdd(ob + (size_t)row * N + col, acc[i][j][r]);
        }
      }
    return;
  }

  // EPI == 2 (direct relu^2 bf16)
  const float cw = fmaxf(wsum[0] * winv, 1e-5f);
#pragma unroll
  for (int i = 0; i < 4; i++) {
#pragma unroll
    for (int r = 0; r < 4; r++) {
      const int row = m0 + wM * 64 + i * 16 + q4 * 4 + r;
      const float sa = sA[row] * cw;
#pragma unroll
      for (int j = 0; j < 4; j++) {
        const int col = n0 + wN * 64 + j * 16 + ml;
        const float val = (float)acc[i][j][r] * sa;
        float u = fmaxf(val, 0.0f);
        ((bf16*)out)[(size_t)row * N + col] = (bf16)(u * u);
      }
    }
  }
}

// ---------------- split-K scale/residual epilogues (i32 acc in) ----------------
// MODE 1: out f32  = resid(flag-typed) + acc*sA[row]*cw (x1)
// MODE 2: out flag-typed = x1(f32) + acc*sA[row]*cw     (final)
template <int MODE>
__global__ __launch_bounds__(256) void k_epi(const int* __restrict__ acc, int lda, int cofs,
                                             int ncols,
                                             const float* __restrict__ sA,
                                             const float* __restrict__ wsum, float winv,
                                             const void* __restrict__ resid,
                                             void* __restrict__ out,
                                             const int* __restrict__ flag) {
  const int row = blockIdx.x, tid = threadIdx.x;
  const float cw = fmaxf(wsum[0] * winv, 1e-5f);
  const float srow = sA[row] * cw;
  const int f32 = flag[0];
  for (int c = tid * 4; c < ncols; c += 1024) {
    const v4i a = *(const v4i*)(acc + (size_t)row * lda + cofs + c);
    const float v0 = (float)a[0] * srow, v1 = (float)a[1] * srow;
    const float v2 = (float)a[2] * srow, v3 = (float)a[3] * srow;
    const size_t o = (size_t)row * ncols + c;
    if (MODE == 1) {
      float4 rv;
      if (f32) {
        rv = *(const float4*)((const float*)resid + o);
      } else {
        const v4bf rb = *(const v4bf*)((const bf16*)resid + o);
        rv = make_float4((float)rb[0], (float)rb[1], (float)rb[2], (float)rb[3]);
      }
      *(float4*)((float*)out + o) = make_float4(rv.x + v0, rv.y + v1, rv.z + v2, rv.w + v3);
    } else {  // MODE 2
      const float4 rv = *(const float4*)((const float*)resid + o);
      const float o0 = rv.x + v0, o1 = rv.y + v1, o2 = rv.z + v2, o3 = rv.w + v3;
      if (f32) {
        *(float4*)((float*)out + o) = make_float4(o0, o1, o2, o3);
      } else {
        v4bf r;
        r[0] = (bf16)o0; r[1] = (bf16)o1; r[2] = (bf16)o2; r[3] = (bf16)o3;
        *(v4bf*)((bf16*)out + o) = r;
      }
    }
  }
}

// fused Q+K epilogue. Q: plain [t][2048]. K: head-major tiled PRE-SWIZZLED layout
// Kh[kvh][t][64]: elem = kvh*131072 + (t>>5)*2048 + (t&31)*64 + (((d>>3)^(t&7))<<3) + (d&7)
// (XOR slot-swizzle within each 32-row 4KB tile; attn's ds_read applies the same XOR)
__global__ __launch_bounds__(256) void k_epiQK(const int* __restrict__ acc,
                                               const float* __restrict__ sA,
                                               const float* __restrict__ wsum,
                                               bf16* __restrict__ Qb, bf16* __restrict__ Kh) {
  const int row = blockIdx.x, tid = threadIdx.x;  // row = token t
  const float cw0 = fmaxf(wsum[0] * INV_D2, 1e-5f);
  const float cw1 = fmaxf(wsum[1] * INV_KV, 1e-5f);
  const float sa = sA[row];
  bf16* kb_ = Kh + ((size_t)(row >> 5) * 2048) + (row & 31) * 64;
  const int rx = row & 7;
  for (int c = tid * 4; c < 2560; c += 1024) {
    const v4i a = *(const v4i*)(acc + (size_t)row * 2560 + c);
    if (c < 2048) {
      v4bf r;
#pragma unroll
      for (int j = 0; j < 4; j++) r[j] = (bf16)((float)a[j] * sa * cw0);
      *(v4bf*)(Qb + (size_t)row * 2048 + c) = r;
    } else {
      const int j0 = c - 2048;
      const int kvh = j0 >> 6, d = j0 & 63;
      v4bf r;
#pragma unroll
      for (int j = 0; j < 4; j++) r[j] = (bf16)((float)a[j] * sa * cw1);
      const int elem = ((((d >> 3) ^ rx) << 3) + (d & 7));
      *(v4bf*)(kb_ + (size_t)kvh * 131072 + elem) = r;
    }
  }
}

// Vt epilogue -> head-major tile-blocked PRE-SWIZZLED V^T:
// Vtb[kvh][tile][64 d][32 t]: elem = kvh*131072 + (t>>5)*2048 + d*32
//                                   + (((t&31)>>3 ^ ((d>>1)&3))<<3) + (t&7)
__global__ __launch_bounds__(256) void k_epiVt(const int* __restrict__ acc,
                                               const float* __restrict__ sT,
                                               const float* __restrict__ wsum,
                                               bf16* __restrict__ Vtb) {
  const int vr = blockIdx.x, tid = threadIdx.x;  // vr = 0..511 (kvh*64 + d)
  const int kvh = vr >> 6, dd = vr & 63;
  const float cw = fmaxf(wsum[2] * INV_KV, 1e-5f);
  const int sw = (dd >> 1) & 3;
  bf16* vb = Vtb + (size_t)kvh * 131072 + dd * 32;
  for (int c = tid * 4; c < 2048; c += 1024) {
    const v4i a = *(const v4i*)(acc + (size_t)vr * 2048 + c);
    const float4 sc = *(const float4*)(sT + c);
    v4bf r;
    r[0] = (bf16)((float)a[0] * sc.x * cw);
    r[1] = (bf16)((float)a[1] * sc.y * cw);
    r[2] = (bf16)((float)a[2] * sc.z * cw);
    r[3] = (bf16)((float)a[3] * sc.w * cw);
    const int tq = c & 31;
    const int elem = (c >> 5) * 2048 + ((((tq >> 3) ^ sw) << 3) + (tq & 7));
    *(v4bf*)(vb + elem) = r;
  }
}

// ---------------- MFMA flash attention (causal, GQA 32q/8kv heads, D=64) ----------------
// r6 softmax structure (KVBLK=32) + coalesced LDS staging:
// K/V tiles (4KB each) staged per-iteration via 8 contiguous 1KB global_load_lds
// from pre-swizzled head-major layouts (fixes address-divergent L1 gathers that
// bounded r2/r6/r7 at ~94us); double-buffered (16KB LDS), vmcnt(0) at loop end
// overlaps next tile's fetch with current compute. Fragment ds_reads use the
// writer's XOR slot-swizzle (residual 4-way conflict ~ 1.58x, m136).
__global__ __launch_bounds__(64) void k_attn(const bf16* __restrict__ Q, const bf16* __restrict__ Kh,
                                             const bf16* __restrict__ Vtb, bf16* __restrict__ O) {
  __shared__ __align__(16) bf16 Kl[2][2048];
  __shared__ __align__(16) bf16 Vl[2][2048];
  const int h = blockIdx.y;
  const int kvh = h >> 2;
  const int t = (blockIdx.x + ((h >> 2) << 3)) & 63;  // balanced q-tile swizzle
  const int qw0 = t * 32;
  const int lane = threadIdx.x;
  const int ql = lane & 31;
  const int hi = lane >> 5;

  v8bf qf[4];
  {
    const bf16* qp = Q + (size_t)(qw0 + ql) * 2048 + h * 64 + hi * 8;
#pragma unroll
    for (int c = 0; c < 4; c++) qf[c] = *(const v8bf*)(qp + c * 16);
  }

  float m = -1e30f, l = 0.0f;
  f32x16 acc0 = {}, acc1 = {};

  const bf16* khead = Kh + (size_t)kvh * 131072 + lane * 8;
  const bf16* vhead = Vtb + (size_t)kvh * 131072 + lane * 8;

  // prologue: stage tile 0 into buffer 0 (coalesced 1KB loads)
#pragma unroll
  for (int cc = 0; cc < 4; cc++) {
    glds16(khead + cc * 512, &Kl[0][cc * 512]);
    glds16(vhead + cc * 512, &Vl[0][cc * 512]);
  }
  asm volatile("s_waitcnt vmcnt(0)" ::: "memory");
  int cb = 0;

  for (int kb = 0; kb <= qw0; kb += 32) {
    if (kb + 32 <= qw0) {  // prefetch next tile into other buffer
      const int tb = ((kb + 32) >> 5) * 2048;
#pragma unroll
      for (int cc = 0; cc < 4; cc++) {
        glds16(khead + tb + cc * 512, &Kl[cb ^ 1][cc * 512]);
        glds16(vhead + tb + cc * 512, &Vl[cb ^ 1][cc * 512]);
      }
    }
    // S^T = K . Q^T from LDS (swizzled ds_read_b128)
    f32x16 s = {};
    {
      const char* kl = (const char*)&Kl[cb][0] + ql * 128;
#pragma unroll
      for (int c = 0; c < 4; c++) {
        const int sl = ((2 * c + hi) ^ (ql & 7)) << 4;
        const v8bf kf = *(const v8bf*)(kl + sl);
        s = MFMA32(kf, qf[c], s);
      }
    }
    const bool diag = (kb == qw0);
    float p[16];
    float rm = -1e30f;
#pragma unroll
    for (int r = 0; r < 16; r++) {
      float v = s[r] * 0.125f;
      const int koff = (r & 3) + ((r >> 2) << 3) + (hi << 2);
      if (diag && koff > ql) v = -1e30f;
      p[r] = v;
      rm = fmaxf(rm, v);
    }
    rm = fmaxf(rm, __shfl_xor(rm, 32));
    const float mn = fmaxf(m, rm);
    const float alpha = __expf(m - mn);
    m = mn;
    float rs = 0.0f;
#pragma unroll
    for (int r = 0; r < 16; r++) {
      p[r] = __expf(p[r] - mn);
      rs += p[r];
    }
    rs += __shfl_xor(rs, 32);
    l = l * alpha + rs;
#pragma unroll
    for (int r = 0; r < 16; r++) { acc0[r] *= alpha; acc1[r] *= alpha; }

    unsigned int w0 = packbf(p[0], p[1]),   w2 = packbf(p[4], p[5]);
    unsigned int w1 = packbf(p[2], p[3]),   w3 = packbf(p[6], p[7]);
    unsigned int x0 = packbf(p[8], p[9]),   x2 = packbf(p[12], p[13]);
    unsigned int x1 = packbf(p[10], p[11]), x3 = packbf(p[14], p[15]);
    asm("v_permlane32_swap_b32 %0, %1" : "+v"(w0), "+v"(w2));
    asm("v_permlane32_swap_b32 %0, %1" : "+v"(w1), "+v"(w3));
    asm("v_permlane32_swap_b32 %0, %1" : "+v"(x0), "+v"(x2));
    asm("v_permlane32_swap_b32 %0, %1" : "+v"(x1), "+v"(x3));
    union BU { unsigned int u[4]; v8bf v; } B0, B1;
    B0.u[0] = w0; B0.u[1] = w1; B0.u[2] = w2; B0.u[3] = w3;
    B1.u[0] = x0; B1.u[1] = x1; B1.u[2] = x2; B1.u[3] = x3;

    // O^T += V^T . P^T from LDS (swizzled)
    {
      const char* vl = (const char*)&Vl[cb][0] + ql * 64;
      const int sx = (ql >> 1) & 3;
      const int sl0 = ((0 + hi) ^ sx) << 4;  // chunk 0: kv 0..15
      const int sl1 = ((2 + hi) ^ sx) << 4;  // chunk 1: kv 16..31
      const v8bf v00 = *(const v8bf*)(vl + sl0);
      const v8bf v01 = *(const v8bf*)(vl + sl1);
      const v8bf v10 = *(const v8bf*)(vl + 2048 + sl0);
      const v8bf v11 = *(const v8bf*)(vl + 2048 + sl1);
      acc0 = MFMA32(v00, B0.v, acc0);
      acc0 = MFMA32(v01, B1.v, acc0);
      acc1 = MFMA32(v10, B0.v, acc1);
      acc1 = MFMA32(v11, B1.v, acc1);
    }
    asm volatile("s_waitcnt vmcnt(0)" ::: "memory");  // next tile landed
    cb ^= 1;
  }

  const float inv = 1.0f / l;
  unsigned int* op = (unsigned int*)(O + (size_t)(qw0 + ql) * 2048 + h * 64);
#pragma unroll
  for (int r = 0; r < 16; r += 2) {
    const int d = (r & 3) + ((r >> 2) << 3) + (hi << 2);
    op[d >> 1] = packbf(acc0[r] * inv, acc0[r + 1] * inv);
    op[(d >> 1) + 16] = packbf(acc1[r] * inv, acc1[r + 1] * inv);
  }
}

// ---------------- launcher ----------------
// Workspace (96 MB + 64 KB), offsets from `big` (MB):
//   0-16   w1z(i8) [->FFN gemm]  ... then fq(i8) after rowq32
//   16-32  w2z(i8)
//   32-36  wqz  36-37 wkz (contiguous [2560][2048])  37-38 wvz  38-42 woz
//   42-46  xq1(i8) [->proj gemms]   ... then oq(i8) after rowq8
//   46-66  accQK(i32) [->epiQK]     ... then accO(i32) [wo gemm->epi1]
//   66-70  accVt(i32) [->epiVt]
//   70-72  Kh  72-74 Vtb  74-82 Qb  [epis->attn]
//   82-90  Ob                       [attn->rowq8]
//   80-96  x1(f32)                  [epi1->end; Qb/Ob dead by then]
//   74-78  xq2(i8)  42-74 Fb(bf16)  [lnq2->gemm2->rowq32]
//   42-58  accF(i32)                [w2 gemm->epi2]
extern "C" void kernel_launch(void* const* d_in, const int* in_sizes, int n_in, void* d_out,
                              int out_size, void* d_ws, size_t ws_size, hipStream_t stream) {
  const void* x = d_in[0];
  const void* g1 = d_in[1];
  const void* b1 = d_in[2];
  const void* g2 = d_in[3];
  const void* b2 = d_in[4];
  const void* wq = d_in[5];
  const void* wk = d_in[6];
  const void* wv = d_in[7];
  const void* wo = d_in[8];
  const void* w1 = d_in[9];
  const void* w2 = d_in[10];

  char* ws = (char*)d_ws;
  const size_t MB = 1ull << 20;
  float* wsum = (float*)ws;
  float* s1 = (float*)(ws + 8192);
  float* so = (float*)(ws + 16384);
  float* s2 = (float*)(ws + 24576);
  float* sf = (float*)(ws + 32768);
  int* flag = (int*)(ws + 40960);
  char* big = ws + 65536;

  i8* w1z = (i8*)(big);
  i8* fq  = (i8*)(big);
  i8* w2z = (i8*)(big + 16 * MB);
  i8* wqz = (i8*)(big + 32 * MB);   // [2560][2048] contiguous with wkz
  i8* wkz = (i8*)(big + 36 * MB);
  i8* wvz = (i8*)(big + 37 * MB);
  i8* woz = (i8*)(big + 38 * MB);
  i8* xq1 = (i8*)(big + 42 * MB);
  i8* oq  = xq1;
  int* accQK = (int*)(big + 46 * MB);   // [2048][2560]
  int* accVt = (int*)(big + 66 * MB);   // [512][2048]
  bf16* Kh   = (bf16*)(big + 70 * MB);  // [8][2048][64] swizzled tiles
  bf16* Vtb  = (bf16*)(big + 72 * MB);  // [8][64][64][32] swizzled tiles
  bf16* Qb   = (bf16*)(big + 74 * MB);
  bf16* Ob   = (bf16*)(big + 82 * MB);
  int* accO  = (int*)(big + 46 * MB);   // [2048][2048]
  float* x1  = (float*)(big + 80 * MB);
  i8* xq2 = (i8*)(big + 74 * MB);
  bf16* Fb   = (bf16*)(big + 42 * MB);  // [2048][8192]
  int* accF  = (int*)(big + 42 * MB);   // [2048][2048]

  k_sniff<<<1, 64, 0, stream>>>((const unsigned short*)x, flag);
  k_zero<<<1, 64, 0, stream>>>(wsum, 8);
  // zero accQK+accVt (contiguous 24MB @46-70)
  k_zerof<<<6144, 256, 0, stream>>>((float4*)accQK);

  k_abssum6<<<672, 256, 0, stream>>>(wq, wk, wv, wo, w1, w2, flag, wsum);
  k_wquant6<<<21504, 256, 0, stream>>>(wq, wk, wv, wo, w1, w2,
                                       wqz, wkz, wvz, woz, w1z, w2z, wsum, flag);

  // ---- attention sublayer ----
  k_lnq<false><<<2048, 256, 0, stream>>>(x, g1, b1, xq1, s1, flag);
  // fused Q+K projection: B = [wqz;wkz] (2560 rows), split-K x4 -> accQK
  k_gemm<4><<<dim3(20, 16, 4), 256, 0, stream>>>(xq1, wqz, s1, wsum + 0, INV_D2, accQK,
                                                 2048, 2560, 2048, 512, flag);
  // V^T directly: C[d][t] = wvz[d].xq1[t], split-K x4 -> accVt
  k_gemm<4><<<dim3(16, 4, 4), 256, 0, stream>>>(wvz, xq1, s1, wsum + 2, INV_KV, accVt,
                                                512, 2048, 2048, 512, flag);
  k_epiQK<<<2048, 256, 0, stream>>>(accQK, s1, wsum, Qb, Kh);
  k_epiVt<<<512, 256, 0, stream>>>(accVt, s1, wsum, Vtb);
  k_attn<<<dim3(64, 32), 64, 0, stream>>>(Qb, Kh, Vtb, Ob);
  k_rowq<8><<<2048, 256, 0, stream>>>(Ob, oq, so);
  k_zerof<<<4096, 256, 0, stream>>>((float4*)accO);  // after epiQK read accQK
  k_gemm<4><<<dim3(16, 16, 4), 256, 0, stream>>>(oq, woz, so, wsum + 3, INV_D2, accO,
                                                 2048, 2048, 2048, 512, flag);
  k_epi<1><<<2048, 256, 0, stream>>>(accO, 2048, 0, 2048, so, wsum + 3, INV_D2, x, x1, flag);

  // ---- FFN sublayer ----
  k_lnq<true><<<2048, 256, 0, stream>>>(x1, g2, b2, xq2, s2, flag);
  k_gemm<2><<<dim3(64, 16, 1), 256, 0, stream>>>(xq2, w1z, s2, wsum + 4, INV_F, Fb,
                                                 2048, 8192, 2048, 2048, flag);
  k_rowq<32><<<2048, 256, 0, stream>>>(Fb, fq, sf);  // fq overwrites dead w1z
  k_zerof<<<4096, 256, 0, stream>>>((float4*)accF);  // after rowq read Fb
  k_gemm<4><<<dim3(16, 16, 4), 256, 0, stream>>>(fq, w2z, sf, wsum + 5, INV_F, accF,
                                                 2048, 2048, 8192, 2048, flag);
  k_epi<2><<<2048, 256, 0, stream>>>(accF, 2048, 0, 2048, sf, wsum + 5, INV_F, x1, d_out, flag);
}